// Round 1
// baseline (875.154 us; speedup 1.0000x reference)
//
#include <hip/hip_runtime.h>

#define NPTS 2048
#define LOG2E 1.4426950408889634f

// ---------------------------------------------------------------------------
// K0: fold BN affine + softmax scale + log2e into combined QKV weights.
// Wp[768][64]: rows 0..255 = Q (x 0.125*log2e), 256..511 = K, 512..767 = V
// ---------------------------------------------------------------------------
__global__ void prep_weights(const float* __restrict__ gamma, const float* __restrict__ beta,
                             const float* __restrict__ q_w, const float* __restrict__ kv_w,
                             float* __restrict__ Wp, float* __restrict__ bp) {
    int j = blockIdx.x * blockDim.x + threadIdx.x;
    if (j >= 768) return;
    const float inv = 1.0f / sqrtf(1.0f + 1e-5f);
    const float* src;
    float scale;
    if (j < 256) { src = q_w + j * 64;         scale = 0.125f * LOG2E; }
    else         { src = kv_w + (j - 256) * 64; scale = 1.0f; }
    float b = 0.f;
    for (int c = 0; c < 64; ++c) {
        float w = src[c];
        Wp[j * 64 + c] = w * gamma[c] * inv * scale;
        b += w * beta[c];
    }
    bp[j] = b * scale;
}

// ---------------------------------------------------------------------------
// K1: QKV GEMM.  qkv[bf][n][0..767] = xs[b][f_src][c][n] contracted with Wp.
// f_src = f01 for Q columns, 3-f01 for K/V columns (xr = xn[::-1]).
// Tile 64n x 64j, K=64, 256 threads, 4x4 microtile.
// ---------------------------------------------------------------------------
__global__ __launch_bounds__(256) void qkv_gemm(const float* __restrict__ xs,
                                                const float* __restrict__ Wp,
                                                const float* __restrict__ bp,
                                                float* __restrict__ qkv) {
    const int bf = blockIdx.z;            // b*2 + f01
    const int b = bf >> 1, f01 = bf & 1;
    const int jt = blockIdx.y;            // 0..11  (j block of 64)
    const int f_src = (jt < 4) ? f01 : (3 - f01);
    const int n0 = blockIdx.x * 64;
    const float* __restrict__ A = xs + (size_t)((b * 4 + f_src) * 64) * NPTS; // [c][n]

    __shared__ float As[64][64];   // [c][n]
    __shared__ float Ws[64][68];   // [j][c], padded stride

    const int t = threadIdx.x;
    const int tx = t & 15, ty = t >> 4;

    for (int r = 0; r < 4; ++r) {
        int row = ty + 16 * r;
        int col = tx * 4;
        *(float4*)&As[row][col] = *(const float4*)&A[(size_t)row * NPTS + n0 + col];
        *(float4*)&Ws[row][col] = *(const float4*)&Wp[(size_t)(jt * 64 + row) * 64 + col];
    }
    __syncthreads();

    // thread owns n = n0 + ty + 16i, j = jt*64 + tx + 16jj
    float acc[4][4];
#pragma unroll
    for (int jj = 0; jj < 4; ++jj) {
        float bv = bp[jt * 64 + tx + 16 * jj];
#pragma unroll
        for (int i = 0; i < 4; ++i) acc[i][jj] = bv;
    }
    for (int c = 0; c < 64; ++c) {
        float a[4], w[4];
#pragma unroll
        for (int i = 0; i < 4; ++i) a[i] = As[c][ty + 16 * i];
#pragma unroll
        for (int jj = 0; jj < 4; ++jj) w[jj] = Ws[tx + 16 * jj][c];
#pragma unroll
        for (int i = 0; i < 4; ++i)
#pragma unroll
            for (int jj = 0; jj < 4; ++jj) acc[i][jj] += a[i] * w[jj];
    }

    float* outp = qkv + (size_t)bf * NPTS * 768;
#pragma unroll
    for (int i = 0; i < 4; ++i) {
        int n = n0 + ty + 16 * i;
#pragma unroll
        for (int jj = 0; jj < 4; ++jj)
            outp[(size_t)n * 768 + jt * 64 + tx + 16 * jj] = acc[i][jj];
    }
}

// ---------------------------------------------------------------------------
// K2: flash attention, f32 VALU.  One block = 64 q rows of one (bf, h).
// Q cols h*64, K cols 256+h*64, V cols 512+h*64 in qkv[bf].
// Online softmax in log2 domain (scale folded into Wq).
// ---------------------------------------------------------------------------
__global__ __launch_bounds__(256) void attn_kernel(const float* __restrict__ qkv,
                                                   float* __restrict__ O) {
    const int combo = blockIdx.y;          // bf*4 + h
    const int bf = combo >> 2, h = combo & 3;
    const int n0 = blockIdx.x * 64;
    const float* __restrict__ base = qkv + (size_t)bf * NPTS * 768;

    __shared__ float Qs[64][68];
    __shared__ float Ks[64][68];
    __shared__ float Vs[64][64];
    __shared__ float Ps[64][68];

    const int t = threadIdx.x;
    const int tx = t & 15, ty = t >> 4;

    for (int r = 0; r < 4; ++r) {
        int row = ty + 16 * r, col = tx * 4;
        *(float4*)&Qs[row][col] = *(const float4*)&base[(size_t)(n0 + row) * 768 + h * 64 + col];
    }

    float m_[4], l_[4], o_[4][4];
#pragma unroll
    for (int a = 0; a < 4; ++a) {
        m_[a] = -1e30f; l_[a] = 0.f;
#pragma unroll
        for (int b = 0; b < 4; ++b) o_[a][b] = 0.f;
    }

    for (int kt = 0; kt < NPTS / 64; ++kt) {
        __syncthreads();   // previous PV done before overwriting K/V
        for (int r = 0; r < 4; ++r) {
            int row = ty + 16 * r, col = tx * 4;
            size_t g = (size_t)(kt * 64 + row) * 768 + h * 64 + col;
            *(float4*)&Ks[row][col] = *(const float4*)&base[g + 256];
            *(float4*)&Vs[row][col] = *(const float4*)&base[g + 512];
        }
        __syncthreads();

        // S = Q.K^T  (already includes 0.125*log2e)
        float s[4][4];
#pragma unroll
        for (int a = 0; a < 4; ++a)
#pragma unroll
            for (int b = 0; b < 4; ++b) s[a][b] = 0.f;

#pragma unroll
        for (int c4 = 0; c4 < 16; ++c4) {
            float4 qa[4], kb[4];
#pragma unroll
            for (int a = 0; a < 4; ++a) qa[a] = *(float4*)&Qs[ty + 16 * a][c4 * 4];
#pragma unroll
            for (int b = 0; b < 4; ++b) kb[b] = *(float4*)&Ks[tx + 16 * b][c4 * 4];
#pragma unroll
            for (int a = 0; a < 4; ++a)
#pragma unroll
                for (int b = 0; b < 4; ++b)
                    s[a][b] += qa[a].x * kb[b].x + qa[a].y * kb[b].y
                             + qa[a].z * kb[b].z + qa[a].w * kb[b].w;
        }

        // online softmax update; thread's q rows are ty+16a, reduce over tx group
#pragma unroll
        for (int a = 0; a < 4; ++a) {
            float v = fmaxf(fmaxf(s[a][0], s[a][1]), fmaxf(s[a][2], s[a][3]));
            v = fmaxf(v, __shfl_xor(v, 1));
            v = fmaxf(v, __shfl_xor(v, 2));
            v = fmaxf(v, __shfl_xor(v, 4));
            v = fmaxf(v, __shfl_xor(v, 8));
            float mnew = fmaxf(m_[a], v);
            float corr = exp2f(m_[a] - mnew);
            m_[a] = mnew;
            float rs = 0.f;
#pragma unroll
            for (int b = 0; b < 4; ++b) {
                float p = exp2f(s[a][b] - mnew);
                Ps[ty + 16 * a][tx + 16 * b] = p;
                rs += p;
            }
            rs += __shfl_xor(rs, 1);
            rs += __shfl_xor(rs, 2);
            rs += __shfl_xor(rs, 4);
            rs += __shfl_xor(rs, 8);
            l_[a] = l_[a] * corr + rs;
#pragma unroll
            for (int b = 0; b < 4; ++b) o_[a][b] *= corr;
        }
        __syncthreads();

        // PV: o[qi][4tx+b] += sum_kj P[qi][kj] * V[kj][4tx+b]
#pragma unroll
        for (int k4 = 0; k4 < 16; ++k4) {
            float4 pa[4], vb[4];
#pragma unroll
            for (int a = 0; a < 4; ++a) pa[a] = *(float4*)&Ps[ty + 16 * a][k4 * 4];
#pragma unroll
            for (int j = 0; j < 4; ++j) vb[j] = *(float4*)&Vs[k4 * 4 + j][tx * 4];
#pragma unroll
            for (int a = 0; a < 4; ++a) {
                o_[a][0] += pa[a].x * vb[0].x + pa[a].y * vb[1].x + pa[a].z * vb[2].x + pa[a].w * vb[3].x;
                o_[a][1] += pa[a].x * vb[0].y + pa[a].y * vb[1].y + pa[a].z * vb[2].y + pa[a].w * vb[3].y;
                o_[a][2] += pa[a].x * vb[0].z + pa[a].y * vb[1].z + pa[a].z * vb[2].z + pa[a].w * vb[3].z;
                o_[a][3] += pa[a].x * vb[0].w + pa[a].y * vb[1].w + pa[a].z * vb[2].w + pa[a].w * vb[3].w;
            }
        }
    }

    float* __restrict__ Op = O + (size_t)combo * NPTS * 64;
#pragma unroll
    for (int a = 0; a < 4; ++a) {
        float inv = 1.0f / l_[a];
        float4 v = make_float4(o_[a][0] * inv, o_[a][1] * inv, o_[a][2] * inv, o_[a][3] * inv);
        *(float4*)&Op[(size_t)(n0 + ty + 16 * a) * 64 + tx * 4] = v;
    }
}

// ---------------------------------------------------------------------------
// K3: xa = (O_f0 + O_f1) @ proj_w.T + proj_b ; frames = xa @ map_w.T + map_b
// h>=1 -> d_out regions; h==0 frames -> ws (chamfer input)
// ---------------------------------------------------------------------------
__global__ __launch_bounds__(256) void proj_frames(const float* __restrict__ O,
                                                   const float* __restrict__ proj_w,
                                                   const float* __restrict__ proj_b,
                                                   const float* __restrict__ map_w,
                                                   const float* __restrict__ map_b,
                                                   float* __restrict__ out,
                                                   float* __restrict__ frames0) {
    const int bh = blockIdx.y, b = bh >> 2, h = bh & 3;
    const int n0 = blockIdx.x * 64;
    const float* __restrict__ O0 = O + ((size_t)((b * 2 + 0) * 4 + h) * NPTS + n0) * 64;
    const float* __restrict__ O1 = O + ((size_t)((b * 2 + 1) * 4 + h) * NPTS + n0) * 64;

    __shared__ float Xs[64][68];
    __shared__ float Ws[64][68];
    __shared__ float xaS[64][68];

    const int t = threadIdx.x;
    const int tx = t & 15, ty = t >> 4;

    for (int r = 0; r < 4; ++r) {
        int row = ty + 16 * r, col = tx * 4;
        float4 x0 = *(const float4*)&O0[(size_t)row * 64 + col];
        float4 x1 = *(const float4*)&O1[(size_t)row * 64 + col];
        x0.x += x1.x; x0.y += x1.y; x0.z += x1.z; x0.w += x1.w;
        *(float4*)&Xs[row][col] = x0;
        *(float4*)&Ws[row][col] = *(const float4*)&proj_w[(size_t)row * 64 + col];
    }
    __syncthreads();

    float acc[4][4];
#pragma unroll
    for (int jj = 0; jj < 4; ++jj) {
        float bv = proj_b[tx + 16 * jj];
#pragma unroll
        for (int i = 0; i < 4; ++i) acc[i][jj] = bv;
    }
    for (int c = 0; c < 64; ++c) {
        float a[4], w[4];
#pragma unroll
        for (int i = 0; i < 4; ++i) a[i] = Xs[ty + 16 * i][c];
#pragma unroll
        for (int jj = 0; jj < 4; ++jj) w[jj] = Ws[tx + 16 * jj][c];
#pragma unroll
        for (int i = 0; i < 4; ++i)
#pragma unroll
            for (int jj = 0; jj < 4; ++jj) acc[i][jj] += a[i] * w[jj];
    }

#pragma unroll
    for (int i = 0; i < 4; ++i)
#pragma unroll
        for (int jj = 0; jj < 4; ++jj)
            xaS[ty + 16 * i][tx + 16 * jj] = acc[i][jj];

    if (h >= 1) {
        float* __restrict__ xa_out = out + (size_t)(b * 3 + h - 1) * NPTS * 64;
#pragma unroll
        for (int i = 0; i < 4; ++i)
#pragma unroll
            for (int jj = 0; jj < 4; ++jj)
                xa_out[(size_t)(n0 + ty + 16 * i) * 64 + tx + 16 * jj] = acc[i][jj];
    }
    __syncthreads();

    if (t < 192) {
        int r = t / 3, j = t % 3;
        float s = map_b[j];
        for (int c = 0; c < 64; ++c) s += xaS[r][c] * map_w[j * 64 + c];
        int n = n0 + r;
        if (h == 0) frames0[((size_t)b * NPTS + n) * 3 + j] = s;
        else        out[786432 + ((size_t)(b * 3 + h - 1) * NPTS + n) * 3 + j] = s;
    }
}

// ---------------------------------------------------------------------------
// K4: chamfer mins.  dir 0: per a-point (pc1t+frames0) min over b-points (pc1t)
//                    dir 1: per b-point min over a-points
// ---------------------------------------------------------------------------
__global__ __launch_bounds__(256) void chamfer_min_kernel(const float* __restrict__ pc1,
                                                          const float* __restrict__ frames0,
                                                          float* __restrict__ mins, int dir) {
    const int b = blockIdx.y;
    const int i = blockIdx.x * 256 + threadIdx.x;
    const float* __restrict__ px = pc1 + (size_t)b * 3 * NPTS;
    const float* __restrict__ fr = frames0 + (size_t)b * NPTS * 3;

    float ax = px[i], ay = px[NPTS + i], az = px[2 * NPTS + i];
    if (dir == 0) { ax += fr[i * 3]; ay += fr[i * 3 + 1]; az += fr[i * 3 + 2]; }
    const float a2 = ax * ax + ay * ay + az * az;

    __shared__ float sx[256], sy[256], sz[256], s2[256];
    float best = 1e30f;
    for (int tile = 0; tile < NPTS / 256; ++tile) {
        __syncthreads();
        int jj = tile * 256 + threadIdx.x;
        float bx = px[jj], by = px[NPTS + jj], bz = px[2 * NPTS + jj];
        if (dir == 1) { bx += fr[jj * 3]; by += fr[jj * 3 + 1]; bz += fr[jj * 3 + 2]; }
        sx[threadIdx.x] = bx; sy[threadIdx.x] = by; sz[threadIdx.x] = bz;
        s2[threadIdx.x] = bx * bx + by * by + bz * bz;
        __syncthreads();
        for (int k = 0; k < 256; ++k) {
            float d = a2 + s2[k] - 2.0f * (ax * sx[k] + ay * sy[k] + az * sz[k]);
            best = fminf(best, d);
        }
    }
    mins[((size_t)dir * 2 + b) * NPTS + i] = best;
}

__global__ void chamfer_reduce(const float* __restrict__ mins, float* __restrict__ loss_out) {
    double s = 0.0;
    for (int idx = threadIdx.x; idx < 4 * NPTS; idx += 256) s += (double)mins[idx];
    __shared__ double sm[256];
    sm[threadIdx.x] = s;
    __syncthreads();
    for (int off = 128; off > 0; off >>= 1) {
        if (threadIdx.x < off) sm[threadIdx.x] += sm[threadIdx.x + off];
        __syncthreads();
    }
    if (threadIdx.x == 0) loss_out[0] = (float)(sm[0] / 4096.0);
}

// ---------------------------------------------------------------------------
extern "C" void kernel_launch(void* const* d_in, const int* in_sizes, int n_in,
                              void* d_out, int out_size, void* d_ws, size_t ws_size,
                              hipStream_t stream) {
    const float* xs     = (const float*)d_in[0];
    const float* pc1    = (const float*)d_in[1];
    // d_in[2] = pc2 (unused by reference)
    const float* gamma  = (const float*)d_in[3];
    const float* beta   = (const float*)d_in[4];
    const float* q_w    = (const float*)d_in[5];
    const float* kv_w   = (const float*)d_in[6];
    const float* proj_w = (const float*)d_in[7];
    const float* proj_b = (const float*)d_in[8];
    const float* map_w  = (const float*)d_in[9];
    const float* map_b  = (const float*)d_in[10];
    float* out = (float*)d_out;

    char* ws = (char*)d_ws;
    float* qkv     = (float*)(ws);                 // 4 * 2048 * 768 f32 = 24 MiB
    float* O       = (float*)(ws + 25165824);      // 16 * 2048 * 64 f32 = 8 MiB
    float* Wp      = (float*)(ws + 33554432);      // 768*64
    float* bp      = (float*)(ws + 33751040);      // 768
    float* frames0 = (float*)(ws + 33754112);      // 2*2048*3
    float* mins    = (float*)(ws + 33803264);      // 4*2048

    hipLaunchKernelGGL(prep_weights, dim3(3), dim3(256), 0, stream,
                       gamma, beta, q_w, kv_w, Wp, bp);
    hipLaunchKernelGGL(qkv_gemm, dim3(32, 12, 4), dim3(256), 0, stream,
                       xs, Wp, bp, qkv);
    hipLaunchKernelGGL(attn_kernel, dim3(32, 16), dim3(256), 0, stream,
                       qkv, O);
    hipLaunchKernelGGL(proj_frames, dim3(32, 8), dim3(256), 0, stream,
                       O, proj_w, proj_b, map_w, map_b, out, frames0);
    hipLaunchKernelGGL(chamfer_min_kernel, dim3(8, 2), dim3(256), 0, stream,
                       pc1, frames0, mins, 0);
    hipLaunchKernelGGL(chamfer_min_kernel, dim3(8, 2), dim3(256), 0, stream,
                       pc1, frames0, mins, 1);
    hipLaunchKernelGGL(chamfer_reduce, dim3(1), dim3(256), 0, stream,
                       mins, out + 823296);
}

// Round 2
// 201.388 us; speedup vs baseline: 4.3456x; 4.3456x over previous
//
#include <hip/hip_runtime.h>
#include <hip/hip_bf16.h>

#define NPTS 2048
#define LOG2E 1.4426950408889634f

typedef short bf16x8 __attribute__((ext_vector_type(8)));
typedef float f32x4 __attribute__((ext_vector_type(4)));
typedef __attribute__((address_space(3))) char lds_char;
typedef __attribute__((address_space(1))) const char glob_char;

// ---------------------------------------------------------------------------
// K0: fold BN affine + softmax scale + log2e into combined QKV weights.
// Wp[768][64]: rows 0..255 = Q (x 0.125*log2e), 256..511 = K, 512..767 = V
// ---------------------------------------------------------------------------
__global__ void prep_weights(const float* __restrict__ gamma, const float* __restrict__ beta,
                             const float* __restrict__ q_w, const float* __restrict__ kv_w,
                             float* __restrict__ Wp, float* __restrict__ bp) {
    int j = blockIdx.x * blockDim.x + threadIdx.x;
    if (j >= 768) return;
    const float inv = 1.0f / sqrtf(1.0f + 1e-5f);
    const float* src;
    float scale;
    if (j < 256) { src = q_w + j * 64;          scale = 0.125f * LOG2E; }
    else         { src = kv_w + (j - 256) * 64; scale = 1.0f; }
    float b = 0.f;
    for (int c = 0; c < 64; ++c) {
        float w = src[c];
        Wp[j * 64 + c] = w * gamma[c] * inv * scale;
        b += w * beta[c];
    }
    bp[j] = b * scale;
}

// ---------------------------------------------------------------------------
// K1: QKV GEMM.  Emits bf16 Qg/Kg [bf][n][256] and transposed bf16 Vt [bf][256][n].
// f_src = f01 for Q columns, 3-f01 for K/V columns (xr = xn[::-1]).
// ---------------------------------------------------------------------------
__global__ __launch_bounds__(256) void qkv_gemm(const float* __restrict__ xs,
                                                const float* __restrict__ Wp,
                                                const float* __restrict__ bp,
                                                __hip_bfloat16* __restrict__ Qg,
                                                __hip_bfloat16* __restrict__ Kg,
                                                __hip_bfloat16* __restrict__ Vtg) {
    const int bf = blockIdx.z;            // b*2 + f01
    const int b = bf >> 1, f01 = bf & 1;
    const int jt = blockIdx.y;            // 0..11  (j block of 64)
    const int f_src = (jt < 4) ? f01 : (3 - f01);
    const int n0 = blockIdx.x * 64;
    const float* __restrict__ A = xs + (size_t)((b * 4 + f_src) * 64) * NPTS; // [c][n]

    __shared__ float As[64][68];   // [c][n] staged; reused as transpose bounce
    __shared__ float Ws[64][68];   // [j][c], padded stride

    const int t = threadIdx.x;
    const int tx = t & 15, ty = t >> 4;

    for (int r = 0; r < 4; ++r) {
        int row = ty + 16 * r;
        int col = tx * 4;
        *(float4*)&As[row][col] = *(const float4*)&A[(size_t)row * NPTS + n0 + col];
        *(float4*)&Ws[row][col] = *(const float4*)&Wp[(size_t)(jt * 64 + row) * 64 + col];
    }
    __syncthreads();

    // thread owns n = n0 + ty + 16i, j = jt*64 + tx + 16jj
    float acc[4][4];
#pragma unroll
    for (int jj = 0; jj < 4; ++jj) {
        float bv = bp[jt * 64 + tx + 16 * jj];
#pragma unroll
        for (int i = 0; i < 4; ++i) acc[i][jj] = bv;
    }
    for (int c = 0; c < 64; ++c) {
        float a[4], w[4];
#pragma unroll
        for (int i = 0; i < 4; ++i) a[i] = As[c][ty + 16 * i];
#pragma unroll
        for (int jj = 0; jj < 4; ++jj) w[jj] = Ws[tx + 16 * jj][c];
#pragma unroll
        for (int i = 0; i < 4; ++i)
#pragma unroll
            for (int jj = 0; jj < 4; ++jj) acc[i][jj] += a[i] * w[jj];
    }

    if (jt < 8) {
        __hip_bfloat16* __restrict__ dst = (jt < 4 ? Qg : Kg) + (size_t)bf * NPTS * 256;
        const int jb = (jt & 3) * 64;
#pragma unroll
        for (int i = 0; i < 4; ++i) {
            int n = n0 + ty + 16 * i;
#pragma unroll
            for (int jj = 0; jj < 4; ++jj)
                dst[(size_t)n * 256 + jb + tx + 16 * jj] = __float2bfloat16(acc[i][jj]);
        }
    } else {
        // V: transpose through LDS, write Vt[c][n] bf16 coalesced
        __syncthreads();
#pragma unroll
        for (int i = 0; i < 4; ++i)
#pragma unroll
            for (int jj = 0; jj < 4; ++jj)
                As[tx + 16 * jj][ty + 16 * i] = acc[i][jj];   // [j_local][n_local]
        __syncthreads();
        const int row = t >> 2, c0 = (t & 3) * 16;
        __hip_bfloat16* __restrict__ dst =
            Vtg + ((size_t)bf * 256 + (jt - 8) * 64 + row) * NPTS + n0 + c0;
#pragma unroll
        for (int c = 0; c < 16; ++c) dst[c] = __float2bfloat16(As[row][c0 + c]);
    }
}

// ---------------------------------------------------------------------------
// K2: MFMA flash attention (bf16 in, f32 accum), no-max softmax in exp2 domain.
// Block: 256 thr = 4 waves, 64 q rows (16/wave).  KV tile 64, double-buffered
// via global_load_lds(16B) with XOR-swizzled source; counted vmcnt.
// ---------------------------------------------------------------------------
__global__ __launch_bounds__(256) void attn_mfma(const __hip_bfloat16* __restrict__ Qg,
                                                 const __hip_bfloat16* __restrict__ Kg,
                                                 const __hip_bfloat16* __restrict__ Vtg,
                                                 float* __restrict__ O) {
    const int combo = blockIdx.y;          // bf*4 + h
    const int bf = combo >> 2, h = combo & 3;
    const int n0 = blockIdx.x * 64;

    __shared__ __align__(16) char smem[40960];
    // [0..16384)        buf0: K tile 8KB | Vt tile 8KB
    // [16384..32768)    buf1
    // [32768..40960)    P per wave, 2KB each

    const int t = threadIdx.x;
    const int lane = t & 63, w = t >> 6;
    const int l15 = lane & 15, g = lane >> 4;
    const int srow = lane >> 3, sslot = lane & 7;   // staging: 8 lanes per row

    // Q A-fragments straight from global: A[i=l15][c = s*32 + g*8 + j]
    const __hip_bfloat16* qbase =
        Qg + ((size_t)bf * NPTS + n0 + w * 16 + l15) * 256 + h * 64 + g * 8;
    bf16x8 qf0 = *(const bf16x8*)(qbase);
    bf16x8 qf1 = *(const bf16x8*)(qbase + 32);

    const __hip_bfloat16* kgb = Kg + (size_t)bf * NPTS * 256 + h * 64;
    const __hip_bfloat16* vgb = Vtg + ((size_t)bf * 256 + h * 64) * NPTS;

    f32x4 oacc[4];
    float lpart[4];
#pragma unroll
    for (int r = 0; r < 4; ++r) { lpart[r] = 0.f; oacc[r] = (f32x4){0.f, 0.f, 0.f, 0.f}; }

    auto stage = [&](int kt, int bsel) {
#pragma unroll
        for (int ii = 0; ii < 2; ++ii) {
            const int rb = w * 16 + ii * 8;
            const int r = rb + srow;
            const int cs = (sslot ^ (r & 7)) * 8;     // pre-swizzled source column
            const __hip_bfloat16* ksrc = kgb + (size_t)(kt * 64 + r) * 256 + cs;
            __builtin_amdgcn_global_load_lds((const glob_char*)ksrc,
                (lds_char*)(smem + bsel * 16384 + rb * 128), 16, 0, 0);
            const __hip_bfloat16* vsrc = vgb + (size_t)r * NPTS + kt * 64 + cs;
            __builtin_amdgcn_global_load_lds((const glob_char*)vsrc,
                (lds_char*)(smem + bsel * 16384 + 8192 + rb * 128), 16, 0, 0);
        }
    };

    stage(0, 0);
    int cur = 0;
    char* const Pw = smem + 32768 + w * 2048;

    for (int kt = 0; kt < NPTS / 64; ++kt) {
        if (kt < NPTS / 64 - 1) {
            stage(kt + 1, cur ^ 1);
            asm volatile("s_waitcnt vmcnt(4)" ::: "memory");
        } else {
            asm volatile("s_waitcnt vmcnt(0)" ::: "memory");
        }
        __builtin_amdgcn_s_barrier();
        asm volatile("" ::: "memory");

        char* const Kt = smem + cur * 16384;
        char* const Vt = Kt + 8192;

        // ---- QK^T: S[16q x 64k] per wave ----
        bf16x8 kf[4][2];
#pragma unroll
        for (int tt = 0; tt < 4; ++tt) {
            const int row = tt * 16 + l15;
#pragma unroll
            for (int s = 0; s < 2; ++s)
                kf[tt][s] = *(const bf16x8*)(Kt + row * 128 + (((s * 4 + g) ^ (row & 7)) << 4));
        }
        f32x4 sacc[4];
#pragma unroll
        for (int tt = 0; tt < 4; ++tt) {
            f32x4 z = (f32x4){0.f, 0.f, 0.f, 0.f};
            z = __builtin_amdgcn_mfma_f32_16x16x32_bf16(qf0, kf[tt][0], z, 0, 0, 0);
            z = __builtin_amdgcn_mfma_f32_16x16x32_bf16(qf1, kf[tt][1], z, 0, 0, 0);
            sacc[tt] = z;
        }

        // ---- P = exp2(S) (scale folded into Wq); write bf16 to wave-local LDS ----
#pragma unroll
        for (int tt = 0; tt < 4; ++tt) {
#pragma unroll
            for (int r = 0; r < 4; ++r) {
                float p = exp2f(fminf(sacc[tt][r], 126.f));
                lpart[r] += p;
                const int prow = g * 4 + r;
                const int col = tt * 16 + l15;
                const int off = prow * 128 + ((((col >> 3)) ^ (prow & 7)) << 4) + ((col & 7) << 1);
                *(__hip_bfloat16*)(Pw + off) = __float2bfloat16(p);
            }
        }

        // ---- PV: O[16q x 64c] += P[16q x 64k] * V[64k x 64c] ----
        bf16x8 pa[2];
#pragma unroll
        for (int s = 0; s < 2; ++s)
            pa[s] = *(const bf16x8*)(Pw + l15 * 128 + (((s * 4 + g) ^ (l15 & 7)) << 4));
#pragma unroll
        for (int ct = 0; ct < 4; ++ct) {
            const int row = ct * 16 + l15;
            f32x4 z = oacc[ct];
#pragma unroll
            for (int s = 0; s < 2; ++s) {
                bf16x8 vf = *(const bf16x8*)(Vt + row * 128 + (((s * 4 + g) ^ (row & 7)) << 4));
                z = __builtin_amdgcn_mfma_f32_16x16x32_bf16(pa[s], vf, z, 0, 0, 0);
            }
            oacc[ct] = z;
        }

        asm volatile("s_waitcnt lgkmcnt(0)" ::: "memory");
        __builtin_amdgcn_s_barrier();
        asm volatile("" ::: "memory");
        cur ^= 1;
    }

    // final row-sum reduce (within 16-lane groups) and normalized writeout
#pragma unroll
    for (int r = 0; r < 4; ++r) {
        float l = lpart[r];
        l += __shfl_xor(l, 1);
        l += __shfl_xor(l, 2);
        l += __shfl_xor(l, 4);
        l += __shfl_xor(l, 8);
        lpart[r] = 1.0f / l;
    }
    float* __restrict__ Op = O + ((size_t)combo * NPTS + n0 + w * 16) * 64;
#pragma unroll
    for (int ct = 0; ct < 4; ++ct)
#pragma unroll
        for (int r = 0; r < 4; ++r)
            Op[(size_t)(g * 4 + r) * 64 + ct * 16 + l15] = oacc[ct][r] * lpart[r];
}

// ---------------------------------------------------------------------------
// K3: xa = (O_f0 + O_f1) @ proj_w.T + proj_b ; frames = xa @ map_w.T + map_b
// ---------------------------------------------------------------------------
__global__ __launch_bounds__(256) void proj_frames(const float* __restrict__ O,
                                                   const float* __restrict__ proj_w,
                                                   const float* __restrict__ proj_b,
                                                   const float* __restrict__ map_w,
                                                   const float* __restrict__ map_b,
                                                   float* __restrict__ out,
                                                   float* __restrict__ frames0) {
    const int bh = blockIdx.y, b = bh >> 2, h = bh & 3;
    const int n0 = blockIdx.x * 64;
    const float* __restrict__ O0 = O + ((size_t)((b * 2 + 0) * 4 + h) * NPTS + n0) * 64;
    const float* __restrict__ O1 = O + ((size_t)((b * 2 + 1) * 4 + h) * NPTS + n0) * 64;

    __shared__ float Xs[64][68];
    __shared__ float Ws[64][68];
    __shared__ float xaS[64][68];

    const int t = threadIdx.x;
    const int tx = t & 15, ty = t >> 4;

    for (int r = 0; r < 4; ++r) {
        int row = ty + 16 * r, col = tx * 4;
        float4 x0 = *(const float4*)&O0[(size_t)row * 64 + col];
        float4 x1 = *(const float4*)&O1[(size_t)row * 64 + col];
        x0.x += x1.x; x0.y += x1.y; x0.z += x1.z; x0.w += x1.w;
        *(float4*)&Xs[row][col] = x0;
        *(float4*)&Ws[row][col] = *(const float4*)&proj_w[(size_t)row * 64 + col];
    }
    __syncthreads();

    float acc[4][4];
#pragma unroll
    for (int jj = 0; jj < 4; ++jj) {
        float bv = proj_b[tx + 16 * jj];
#pragma unroll
        for (int i = 0; i < 4; ++i) acc[i][jj] = bv;
    }
    for (int c = 0; c < 64; ++c) {
        float a[4], w[4];
#pragma unroll
        for (int i = 0; i < 4; ++i) a[i] = Xs[ty + 16 * i][c];
#pragma unroll
        for (int jj = 0; jj < 4; ++jj) w[jj] = Ws[tx + 16 * jj][c];
#pragma unroll
        for (int i = 0; i < 4; ++i)
#pragma unroll
            for (int jj = 0; jj < 4; ++jj) acc[i][jj] += a[i] * w[jj];
    }

#pragma unroll
    for (int i = 0; i < 4; ++i)
#pragma unroll
        for (int jj = 0; jj < 4; ++jj)
            xaS[ty + 16 * i][tx + 16 * jj] = acc[i][jj];

    if (h >= 1) {
        float* __restrict__ xa_out = out + (size_t)(b * 3 + h - 1) * NPTS * 64;
#pragma unroll
        for (int i = 0; i < 4; ++i)
#pragma unroll
            for (int jj = 0; jj < 4; ++jj)
                xa_out[(size_t)(n0 + ty + 16 * i) * 64 + tx + 16 * jj] = acc[i][jj];
    }
    __syncthreads();

    if (t < 192) {
        int r = t / 3, j = t % 3;
        float s = map_b[j];
        for (int c = 0; c < 64; ++c) s += xaS[r][c] * map_w[j * 64 + c];
        int n = n0 + r;
        if (h == 0) frames0[((size_t)b * NPTS + n) * 3 + j] = s;
        else        out[786432 + ((size_t)(b * 3 + h - 1) * NPTS + n) * 3 + j] = s;
    }
}

// ---------------------------------------------------------------------------
// K4: chamfer mins, both directions in one dispatch (dir = blockIdx.z)
// ---------------------------------------------------------------------------
__global__ __launch_bounds__(256) void chamfer_min_kernel(const float* __restrict__ pc1,
                                                          const float* __restrict__ frames0,
                                                          float* __restrict__ mins) {
    const int b = blockIdx.y;
    const int dir = blockIdx.z;
    const int i = blockIdx.x * 256 + threadIdx.x;
    const float* __restrict__ px = pc1 + (size_t)b * 3 * NPTS;
    const float* __restrict__ fr = frames0 + (size_t)b * NPTS * 3;

    float ax = px[i], ay = px[NPTS + i], az = px[2 * NPTS + i];
    if (dir == 0) { ax += fr[i * 3]; ay += fr[i * 3 + 1]; az += fr[i * 3 + 2]; }
    const float a2 = ax * ax + ay * ay + az * az;

    __shared__ float sx[256], sy[256], sz[256], s2[256];
    float best = 1e30f;
    for (int tile = 0; tile < NPTS / 256; ++tile) {
        __syncthreads();
        int jj = tile * 256 + threadIdx.x;
        float bx = px[jj], by = px[NPTS + jj], bz = px[2 * NPTS + jj];
        if (dir == 1) { bx += fr[jj * 3]; by += fr[jj * 3 + 1]; bz += fr[jj * 3 + 2]; }
        sx[threadIdx.x] = bx; sy[threadIdx.x] = by; sz[threadIdx.x] = bz;
        s2[threadIdx.x] = bx * bx + by * by + bz * bz;
        __syncthreads();
        for (int k = 0; k < 256; ++k) {
            float d = a2 + s2[k] - 2.0f * (ax * sx[k] + ay * sy[k] + az * sz[k]);
            best = fminf(best, d);
        }
    }
    mins[((size_t)dir * 2 + b) * NPTS + i] = best;
}

__global__ void chamfer_reduce(const float* __restrict__ mins, float* __restrict__ loss_out) {
    double s = 0.0;
    for (int idx = threadIdx.x; idx < 4 * NPTS; idx += 256) s += (double)mins[idx];
    __shared__ double sm[256];
    sm[threadIdx.x] = s;
    __syncthreads();
    for (int off = 128; off > 0; off >>= 1) {
        if (threadIdx.x < off) sm[threadIdx.x] += sm[threadIdx.x + off];
        __syncthreads();
    }
    if (threadIdx.x == 0) loss_out[0] = (float)(sm[0] / 4096.0);
}

// ---------------------------------------------------------------------------
extern "C" void kernel_launch(void* const* d_in, const int* in_sizes, int n_in,
                              void* d_out, int out_size, void* d_ws, size_t ws_size,
                              hipStream_t stream) {
    const float* xs     = (const float*)d_in[0];
    const float* pc1    = (const float*)d_in[1];
    // d_in[2] = pc2 (unused by reference)
    const float* gamma  = (const float*)d_in[3];
    const float* beta   = (const float*)d_in[4];
    const float* q_w    = (const float*)d_in[5];
    const float* kv_w   = (const float*)d_in[6];
    const float* proj_w = (const float*)d_in[7];
    const float* proj_b = (const float*)d_in[8];
    const float* map_w  = (const float*)d_in[9];
    const float* map_b  = (const float*)d_in[10];
    float* out = (float*)d_out;

    char* ws = (char*)d_ws;
    __hip_bfloat16* Qg  = (__hip_bfloat16*)(ws);              // 4*2048*256*2 = 4 MiB
    __hip_bfloat16* Kg  = (__hip_bfloat16*)(ws + 4194304);    // 4 MiB
    __hip_bfloat16* Vtg = (__hip_bfloat16*)(ws + 8388608);    // 4 MiB
    float* O       = (float*)(ws + 12582912);                 // 16*2048*64*4 = 8 MiB
    float* Wp      = (float*)(ws + 20971520);                 // 768*64*4
    float* bp      = (float*)(ws + 21168128);                 // 768*4
    float* frames0 = (float*)(ws + 21171200);                 // 2*2048*3*4
    float* mins    = (float*)(ws + 21220352);                 // 4*2048*4

    hipLaunchKernelGGL(prep_weights, dim3(3), dim3(256), 0, stream,
                       gamma, beta, q_w, kv_w, Wp, bp);
    hipLaunchKernelGGL(qkv_gemm, dim3(32, 12, 4), dim3(256), 0, stream,
                       xs, Wp, bp, Qg, Kg, Vtg);
    hipLaunchKernelGGL(attn_mfma, dim3(32, 16), dim3(256), 0, stream,
                       Qg, Kg, Vtg, O);
    hipLaunchKernelGGL(proj_frames, dim3(32, 8), dim3(256), 0, stream,
                       O, proj_w, proj_b, map_w, map_b, out, frames0);
    hipLaunchKernelGGL(chamfer_min_kernel, dim3(8, 2, 2), dim3(256), 0, stream,
                       pc1, frames0, mins);
    hipLaunchKernelGGL(chamfer_reduce, dim3(1), dim3(256), 0, stream,
                       mins, out + 823296);
}

// Round 3
// 98.061 us; speedup vs baseline: 8.9245x; 2.0537x over previous
//
#include <hip/hip_runtime.h>
#include <hip/hip_bf16.h>

#define NPTS 2048
#define LOG2E 1.4426950408889634f
#define NJC 16     // chamfer j-chunks
#define JCH 128    // points per chunk

typedef short bf16x8 __attribute__((ext_vector_type(8)));
typedef float f32x4 __attribute__((ext_vector_type(4)));
typedef __attribute__((address_space(3))) char lds_char;
typedef __attribute__((address_space(1))) const char glob_char;

// ---------------------------------------------------------------------------
// K0: fold BN affine + softmax scale + log2e into combined QKV weights.
// Wp[768][64]: rows 0..255 = Q (x 0.125*log2e), 256..511 = K, 512..767 = V
// ---------------------------------------------------------------------------
__global__ void prep_weights(const float* __restrict__ gamma, const float* __restrict__ beta,
                             const float* __restrict__ q_w, const float* __restrict__ kv_w,
                             float* __restrict__ Wp, float* __restrict__ bp) {
    int j = blockIdx.x * blockDim.x + threadIdx.x;
    if (j >= 768) return;
    const float inv = 1.0f / sqrtf(1.0f + 1e-5f);
    const float* src;
    float scale;
    if (j < 256) { src = q_w + j * 64;          scale = 0.125f * LOG2E; }
    else         { src = kv_w + (j - 256) * 64; scale = 1.0f; }
    float b = 0.f;
    for (int c = 0; c < 64; ++c) {
        float w = src[c];
        Wp[j * 64 + c] = w * gamma[c] * inv * scale;
        b += w * beta[c];
    }
    bp[j] = b * scale;
}

// ---------------------------------------------------------------------------
// K1: QKV GEMM.  Emits bf16 Qg/Kg [bf][n][256] and transposed bf16 Vt [bf][256][n].
// f_src = f01 for Q columns, 3-f01 for K/V columns (xr = xn[::-1]).
// ---------------------------------------------------------------------------
__global__ __launch_bounds__(256) void qkv_gemm(const float* __restrict__ xs,
                                                const float* __restrict__ Wp,
                                                const float* __restrict__ bp,
                                                __hip_bfloat16* __restrict__ Qg,
                                                __hip_bfloat16* __restrict__ Kg,
                                                __hip_bfloat16* __restrict__ Vtg) {
    const int bf = blockIdx.z;            // b*2 + f01
    const int b = bf >> 1, f01 = bf & 1;
    const int jt = blockIdx.y;            // 0..11  (j block of 64)
    const int f_src = (jt < 4) ? f01 : (3 - f01);
    const int n0 = blockIdx.x * 64;
    const float* __restrict__ A = xs + (size_t)((b * 4 + f_src) * 64) * NPTS; // [c][n]

    __shared__ float As[64][68];   // [c][n] staged; reused as transpose bounce
    __shared__ float Ws[64][68];   // [j][c], padded stride

    const int t = threadIdx.x;
    const int tx = t & 15, ty = t >> 4;

    for (int r = 0; r < 4; ++r) {
        int row = ty + 16 * r;
        int col = tx * 4;
        *(float4*)&As[row][col] = *(const float4*)&A[(size_t)row * NPTS + n0 + col];
        *(float4*)&Ws[row][col] = *(const float4*)&Wp[(size_t)(jt * 64 + row) * 64 + col];
    }
    __syncthreads();

    // thread owns n = n0 + ty + 16i, j = jt*64 + tx + 16jj
    float acc[4][4];
#pragma unroll
    for (int jj = 0; jj < 4; ++jj) {
        float bv = bp[jt * 64 + tx + 16 * jj];
#pragma unroll
        for (int i = 0; i < 4; ++i) acc[i][jj] = bv;
    }
    for (int c = 0; c < 64; ++c) {
        float a[4], w[4];
#pragma unroll
        for (int i = 0; i < 4; ++i) a[i] = As[c][ty + 16 * i];
#pragma unroll
        for (int jj = 0; jj < 4; ++jj) w[jj] = Ws[tx + 16 * jj][c];
#pragma unroll
        for (int i = 0; i < 4; ++i)
#pragma unroll
            for (int jj = 0; jj < 4; ++jj) acc[i][jj] += a[i] * w[jj];
    }

    if (jt < 8) {
        __hip_bfloat16* __restrict__ dst = (jt < 4 ? Qg : Kg) + (size_t)bf * NPTS * 256;
        const int jb = (jt & 3) * 64;
#pragma unroll
        for (int i = 0; i < 4; ++i) {
            int n = n0 + ty + 16 * i;
#pragma unroll
            for (int jj = 0; jj < 4; ++jj)
                dst[(size_t)n * 256 + jb + tx + 16 * jj] = __float2bfloat16(acc[i][jj]);
        }
    } else {
        // V: transpose through LDS, write Vt[c][n] bf16 coalesced
        __syncthreads();
#pragma unroll
        for (int i = 0; i < 4; ++i)
#pragma unroll
            for (int jj = 0; jj < 4; ++jj)
                As[tx + 16 * jj][ty + 16 * i] = acc[i][jj];   // [j_local][n_local]
        __syncthreads();
        const int row = t >> 2, c0 = (t & 3) * 16;
        __hip_bfloat16* __restrict__ dst =
            Vtg + ((size_t)bf * 256 + (jt - 8) * 64 + row) * NPTS + n0 + c0;
#pragma unroll
        for (int c = 0; c < 16; ++c) dst[c] = __float2bfloat16(As[row][c0 + c]);
    }
}

// ---------------------------------------------------------------------------
// K2: MFMA flash attention (bf16 in, f32 accum), no-max softmax in exp2 domain.
// Block: 256 thr = 4 waves, 64 q rows (16/wave).  KV tile 64, double-buffered
// via global_load_lds(16B) with XOR-swizzled source; counted vmcnt.
// ---------------------------------------------------------------------------
__global__ __launch_bounds__(256) void attn_mfma(const __hip_bfloat16* __restrict__ Qg,
                                                 const __hip_bfloat16* __restrict__ Kg,
                                                 const __hip_bfloat16* __restrict__ Vtg,
                                                 float* __restrict__ O) {
    const int combo = blockIdx.y;          // bf*4 + h
    const int bf = combo >> 2, h = combo & 3;
    const int n0 = blockIdx.x * 64;

    __shared__ __align__(16) char smem[40960];
    // [0..16384)        buf0: K tile 8KB | Vt tile 8KB
    // [16384..32768)    buf1
    // [32768..40960)    P per wave, 2KB each

    const int t = threadIdx.x;
    const int lane = t & 63, w = t >> 6;
    const int l15 = lane & 15, g = lane >> 4;
    const int srow = lane >> 3, sslot = lane & 7;   // staging: 8 lanes per row

    // Q A-fragments straight from global: A[i=l15][c = s*32 + g*8 + j]
    const __hip_bfloat16* qbase =
        Qg + ((size_t)bf * NPTS + n0 + w * 16 + l15) * 256 + h * 64 + g * 8;
    bf16x8 qf0 = *(const bf16x8*)(qbase);
    bf16x8 qf1 = *(const bf16x8*)(qbase + 32);

    const __hip_bfloat16* kgb = Kg + (size_t)bf * NPTS * 256 + h * 64;
    const __hip_bfloat16* vgb = Vtg + ((size_t)bf * 256 + h * 64) * NPTS;

    f32x4 oacc[4];
    float lpart[4];
#pragma unroll
    for (int r = 0; r < 4; ++r) { lpart[r] = 0.f; oacc[r] = (f32x4){0.f, 0.f, 0.f, 0.f}; }

    auto stage = [&](int kt, int bsel) {
#pragma unroll
        for (int ii = 0; ii < 2; ++ii) {
            const int rb = w * 16 + ii * 8;
            const int r = rb + srow;
            const int cs = (sslot ^ (r & 7)) * 8;     // pre-swizzled source column
            const __hip_bfloat16* ksrc = kgb + (size_t)(kt * 64 + r) * 256 + cs;
            __builtin_amdgcn_global_load_lds((const glob_char*)ksrc,
                (lds_char*)(smem + bsel * 16384 + rb * 128), 16, 0, 0);
            const __hip_bfloat16* vsrc = vgb + (size_t)r * NPTS + kt * 64 + cs;
            __builtin_amdgcn_global_load_lds((const glob_char*)vsrc,
                (lds_char*)(smem + bsel * 16384 + 8192 + rb * 128), 16, 0, 0);
        }
    };

    stage(0, 0);
    int cur = 0;
    char* const Pw = smem + 32768 + w * 2048;

    for (int kt = 0; kt < NPTS / 64; ++kt) {
        if (kt < NPTS / 64 - 1) {
            stage(kt + 1, cur ^ 1);
            asm volatile("s_waitcnt vmcnt(4)" ::: "memory");
        } else {
            asm volatile("s_waitcnt vmcnt(0)" ::: "memory");
        }
        __builtin_amdgcn_s_barrier();
        asm volatile("" ::: "memory");

        char* const Kt = smem + cur * 16384;
        char* const Vt = Kt + 8192;

        // ---- QK^T: S[16q x 64k] per wave ----
        bf16x8 kf[4][2];
#pragma unroll
        for (int tt = 0; tt < 4; ++tt) {
            const int row = tt * 16 + l15;
#pragma unroll
            for (int s = 0; s < 2; ++s)
                kf[tt][s] = *(const bf16x8*)(Kt + row * 128 + (((s * 4 + g) ^ (row & 7)) << 4));
        }
        f32x4 sacc[4];
#pragma unroll
        for (int tt = 0; tt < 4; ++tt) {
            f32x4 z = (f32x4){0.f, 0.f, 0.f, 0.f};
            z = __builtin_amdgcn_mfma_f32_16x16x32_bf16(qf0, kf[tt][0], z, 0, 0, 0);
            z = __builtin_amdgcn_mfma_f32_16x16x32_bf16(qf1, kf[tt][1], z, 0, 0, 0);
            sacc[tt] = z;
        }

        // ---- P = exp2(S) (scale folded into Wq); write bf16 to wave-local LDS ----
#pragma unroll
        for (int tt = 0; tt < 4; ++tt) {
#pragma unroll
            for (int r = 0; r < 4; ++r) {
                float p = exp2f(fminf(sacc[tt][r], 126.f));
                lpart[r] += p;
                const int prow = g * 4 + r;
                const int col = tt * 16 + l15;
                const int off = prow * 128 + ((((col >> 3)) ^ (prow & 7)) << 4) + ((col & 7) << 1);
                *(__hip_bfloat16*)(Pw + off) = __float2bfloat16(p);
            }
        }

        // ---- PV: O[16q x 64c] += P[16q x 64k] * V[64k x 64c] ----
        bf16x8 pa[2];
#pragma unroll
        for (int s = 0; s < 2; ++s)
            pa[s] = *(const bf16x8*)(Pw + l15 * 128 + (((s * 4 + g) ^ (l15 & 7)) << 4));
#pragma unroll
        for (int ct = 0; ct < 4; ++ct) {
            const int row = ct * 16 + l15;
            f32x4 z = oacc[ct];
#pragma unroll
            for (int s = 0; s < 2; ++s) {
                bf16x8 vf = *(const bf16x8*)(Vt + row * 128 + (((s * 4 + g) ^ (row & 7)) << 4));
                z = __builtin_amdgcn_mfma_f32_16x16x32_bf16(pa[s], vf, z, 0, 0, 0);
            }
            oacc[ct] = z;
        }

        asm volatile("s_waitcnt lgkmcnt(0)" ::: "memory");
        __builtin_amdgcn_s_barrier();
        asm volatile("" ::: "memory");
        cur ^= 1;
    }

    // final row-sum reduce (within 16-lane groups) and normalized writeout
#pragma unroll
    for (int r = 0; r < 4; ++r) {
        float l = lpart[r];
        l += __shfl_xor(l, 1);
        l += __shfl_xor(l, 2);
        l += __shfl_xor(l, 4);
        l += __shfl_xor(l, 8);
        lpart[r] = 1.0f / l;
    }
    float* __restrict__ Op = O + ((size_t)combo * NPTS + n0 + w * 16) * 64;
#pragma unroll
    for (int ct = 0; ct < 4; ++ct)
#pragma unroll
        for (int r = 0; r < 4; ++r)
            Op[(size_t)(g * 4 + r) * 64 + ct * 16 + l15] = oacc[ct][r] * lpart[r];
}

// ---------------------------------------------------------------------------
// K3: xa = (O_f0 + O_f1) @ proj_w.T + proj_b ; frames = xa @ map_w.T + map_b
// ---------------------------------------------------------------------------
__global__ __launch_bounds__(256) void proj_frames(const float* __restrict__ O,
                                                   const float* __restrict__ proj_w,
                                                   const float* __restrict__ proj_b,
                                                   const float* __restrict__ map_w,
                                                   const float* __restrict__ map_b,
                                                   float* __restrict__ out,
                                                   float* __restrict__ frames0) {
    const int bh = blockIdx.y, b = bh >> 2, h = bh & 3;
    const int n0 = blockIdx.x * 64;
    const float* __restrict__ O0 = O + ((size_t)((b * 2 + 0) * 4 + h) * NPTS + n0) * 64;
    const float* __restrict__ O1 = O + ((size_t)((b * 2 + 1) * 4 + h) * NPTS + n0) * 64;

    __shared__ float Xs[64][68];
    __shared__ float Ws[64][68];
    __shared__ float xaS[64][68];

    const int t = threadIdx.x;
    const int tx = t & 15, ty = t >> 4;

    for (int r = 0; r < 4; ++r) {
        int row = ty + 16 * r, col = tx * 4;
        float4 x0 = *(const float4*)&O0[(size_t)row * 64 + col];
        float4 x1 = *(const float4*)&O1[(size_t)row * 64 + col];
        x0.x += x1.x; x0.y += x1.y; x0.z += x1.z; x0.w += x1.w;
        *(float4*)&Xs[row][col] = x0;
        *(float4*)&Ws[row][col] = *(const float4*)&proj_w[(size_t)row * 64 + col];
    }
    __syncthreads();

    float acc[4][4];
#pragma unroll
    for (int jj = 0; jj < 4; ++jj) {
        float bv = proj_b[tx + 16 * jj];
#pragma unroll
        for (int i = 0; i < 4; ++i) acc[i][jj] = bv;
    }
    for (int c = 0; c < 64; ++c) {
        float a[4], w[4];
#pragma unroll
        for (int i = 0; i < 4; ++i) a[i] = Xs[ty + 16 * i][c];
#pragma unroll
        for (int jj = 0; jj < 4; ++jj) w[jj] = Ws[tx + 16 * jj][c];
#pragma unroll
        for (int i = 0; i < 4; ++i)
#pragma unroll
            for (int jj = 0; jj < 4; ++jj) acc[i][jj] += a[i] * w[jj];
    }

#pragma unroll
    for (int i = 0; i < 4; ++i)
#pragma unroll
        for (int jj = 0; jj < 4; ++jj)
            xaS[ty + 16 * i][tx + 16 * jj] = acc[i][jj];

    if (h >= 1) {
        float* __restrict__ xa_out = out + (size_t)(b * 3 + h - 1) * NPTS * 64;
#pragma unroll
        for (int i = 0; i < 4; ++i)
#pragma unroll
            for (int jj = 0; jj < 4; ++jj)
                xa_out[(size_t)(n0 + ty + 16 * i) * 64 + tx + 16 * jj] = acc[i][jj];
    }
    __syncthreads();

    if (t < 192) {
        int r = t / 3, j = t % 3;
        float s = map_b[j];
        for (int c = 0; c < 64; ++c) s += xaS[r][c] * map_w[j * 64 + c];
        int n = n0 + r;
        if (h == 0) frames0[((size_t)b * NPTS + n) * 3 + j] = s;
        else        out[786432 + ((size_t)(b * 3 + h - 1) * NPTS + n) * 3 + j] = s;
    }
}

// ---------------------------------------------------------------------------
// K4a: chamfer partial mins.  grid (NPTS/256, NJC, 4); z = dir*2 + b.
// Each block: 256 a-points vs one LDS-resident chunk of 128 b-points.
// ---------------------------------------------------------------------------
__global__ __launch_bounds__(256) void chamfer_partial(const float* __restrict__ pc1,
                                                       const float* __restrict__ frames0,
                                                       float* __restrict__ partial) {
    const int z = blockIdx.z;          // dir*2 + b
    const int dir = z >> 1, b = z & 1;
    const int i = blockIdx.x * 256 + threadIdx.x;
    const int j0 = blockIdx.y * JCH;
    const float* __restrict__ px = pc1 + (size_t)b * 3 * NPTS;
    const float* __restrict__ fr = frames0 + (size_t)b * NPTS * 3;

    __shared__ float4 sj[JCH];
    if (threadIdx.x < JCH) {
        int jj = j0 + threadIdx.x;
        float bx = px[jj], by = px[NPTS + jj], bz = px[2 * NPTS + jj];
        if (dir == 1) { bx += fr[jj * 3]; by += fr[jj * 3 + 1]; bz += fr[jj * 3 + 2]; }
        sj[threadIdx.x] = make_float4(bx, by, bz, bx * bx + by * by + bz * bz);
    }
    float ax = px[i], ay = px[NPTS + i], az = px[2 * NPTS + i];
    if (dir == 0) { ax += fr[i * 3]; ay += fr[i * 3 + 1]; az += fr[i * 3 + 2]; }
    const float a2 = ax * ax + ay * ay + az * az;
    __syncthreads();

    float best = 1e30f;
#pragma unroll 4
    for (int k = 0; k < JCH; ++k) {
        float4 p = sj[k];
        float d = a2 + p.w - 2.0f * (ax * p.x + ay * p.y + az * p.z);
        best = fminf(best, d);
    }
    partial[((size_t)z * NJC + blockIdx.y) * NPTS + i] = best;
}

// ---------------------------------------------------------------------------
// K4b: min over chunks + per-block sum. 32 blocks x 256 thr; gid = z*2048 + i.
// ---------------------------------------------------------------------------
__global__ __launch_bounds__(256) void chamfer_minsum(const float* __restrict__ partial,
                                                      double* __restrict__ sums) {
    const int gid = blockIdx.x * 256 + threadIdx.x;
    const int z = gid >> 11, i = gid & 2047;
    float best = 1e30f;
#pragma unroll
    for (int c = 0; c < NJC; ++c)
        best = fminf(best, partial[((size_t)z * NJC + c) * NPTS + i]);
    __shared__ double sm[256];
    sm[threadIdx.x] = (double)best;
    __syncthreads();
    for (int off = 128; off > 0; off >>= 1) {
        if (threadIdx.x < off) sm[threadIdx.x] += sm[threadIdx.x + off];
        __syncthreads();
    }
    if (threadIdx.x == 0) sums[blockIdx.x] = sm[0];
}

__global__ void chamfer_final(const double* __restrict__ sums, float* __restrict__ loss_out) {
    if (threadIdx.x == 0) {
        double s = 0.0;
        for (int k = 0; k < 32; ++k) s += sums[k];
        loss_out[0] = (float)(s / 4096.0);
    }
}

// ---------------------------------------------------------------------------
extern "C" void kernel_launch(void* const* d_in, const int* in_sizes, int n_in,
                              void* d_out, int out_size, void* d_ws, size_t ws_size,
                              hipStream_t stream) {
    const float* xs     = (const float*)d_in[0];
    const float* pc1    = (const float*)d_in[1];
    // d_in[2] = pc2 (unused by reference)
    const float* gamma  = (const float*)d_in[3];
    const float* beta   = (const float*)d_in[4];
    const float* q_w    = (const float*)d_in[5];
    const float* kv_w   = (const float*)d_in[6];
    const float* proj_w = (const float*)d_in[7];
    const float* proj_b = (const float*)d_in[8];
    const float* map_w  = (const float*)d_in[9];
    const float* map_b  = (const float*)d_in[10];
    float* out = (float*)d_out;

    char* ws = (char*)d_ws;
    __hip_bfloat16* Qg  = (__hip_bfloat16*)(ws);              // 4*2048*256*2 = 4 MiB
    __hip_bfloat16* Kg  = (__hip_bfloat16*)(ws + 4194304);    // 4 MiB
    __hip_bfloat16* Vtg = (__hip_bfloat16*)(ws + 8388608);    // 4 MiB
    float* O       = (float*)(ws + 12582912);                 // 16*2048*64*4 = 8 MiB
    float* Wp      = (float*)(ws + 20971520);                 // 768*64*4
    float* bp      = (float*)(ws + 21168128);                 // 768*4
    float* frames0 = (float*)(ws + 21171200);                 // 2*2048*3*4
    float* partial = (float*)(ws + 21220352);                 // 4*16*2048*4 = 512 KiB
    double* sums   = (double*)(ws + 21744640);                // 32*8

    hipLaunchKernelGGL(prep_weights, dim3(3), dim3(256), 0, stream,
                       gamma, beta, q_w, kv_w, Wp, bp);
    hipLaunchKernelGGL(qkv_gemm, dim3(32, 12, 4), dim3(256), 0, stream,
                       xs, Wp, bp, Qg, Kg, Vtg);
    hipLaunchKernelGGL(attn_mfma, dim3(32, 16), dim3(256), 0, stream,
                       Qg, Kg, Vtg, O);
    hipLaunchKernelGGL(proj_frames, dim3(32, 8), dim3(256), 0, stream,
                       O, proj_w, proj_b, map_w, map_b, out, frames0);
    hipLaunchKernelGGL(chamfer_partial, dim3(NPTS / 256, NJC, 4), dim3(256), 0, stream,
                       pc1, frames0, partial);
    hipLaunchKernelGGL(chamfer_minsum, dim3(32), dim3(256), 0, stream,
                       partial, sums);
    hipLaunchKernelGGL(chamfer_final, dim3(1), dim3(64), 0, stream,
                       sums, out + 823296);
}

// Round 4
// 92.957 us; speedup vs baseline: 9.4146x; 1.0549x over previous
//
#include <hip/hip_runtime.h>
#include <hip/hip_bf16.h>

#define NPTS 2048
#define LOG2E 1.4426950408889634f
#define NJC 16     // chamfer j-chunks
#define JCH 128    // points per chunk

typedef short bf16x8 __attribute__((ext_vector_type(8)));
typedef float f32x4 __attribute__((ext_vector_type(4)));
typedef unsigned uint32x4 __attribute__((ext_vector_type(4)));
typedef __attribute__((address_space(3))) char lds_char;
typedef __attribute__((address_space(1))) const char glob_char;

union PBU { uint32x4 u; bf16x8 v; };

static __device__ __forceinline__ unsigned cvt_pk_bf16(float a, float b) {
    unsigned r;
    asm("v_cvt_pk_bf16_f32 %0, %1, %2" : "=v"(r) : "v"(a), "v"(b));
    return r;
}

// ---------------------------------------------------------------------------
// K0: fold BN affine + softmax scale + log2e into combined QKV weights.
// Wp[768][64]: rows 0..255 = Q (x 0.125*log2e), 256..511 = K, 512..767 = V
// ---------------------------------------------------------------------------
__global__ void prep_weights(const float* __restrict__ gamma, const float* __restrict__ beta,
                             const float* __restrict__ q_w, const float* __restrict__ kv_w,
                             float* __restrict__ Wp, float* __restrict__ bp) {
    int j = blockIdx.x * blockDim.x + threadIdx.x;
    if (j >= 768) return;
    const float inv = 1.0f / sqrtf(1.0f + 1e-5f);
    const float* src;
    float scale;
    if (j < 256) { src = q_w + j * 64;          scale = 0.125f * LOG2E; }
    else         { src = kv_w + (j - 256) * 64; scale = 1.0f; }
    float b = 0.f;
    for (int c = 0; c < 64; ++c) {
        float w = src[c];
        Wp[j * 64 + c] = w * gamma[c] * inv * scale;
        b += w * beta[c];
    }
    bp[j] = b * scale;
}

// ---------------------------------------------------------------------------
// K1: QKV GEMM.  Emits bf16 Qg/Kg [bf][n][256] and transposed bf16 Vt [bf][256][n].
// f_src = f01 for Q columns, 3-f01 for K/V columns (xr = xn[::-1]).
// ---------------------------------------------------------------------------
__global__ __launch_bounds__(256) void qkv_gemm(const float* __restrict__ xs,
                                                const float* __restrict__ Wp,
                                                const float* __restrict__ bp,
                                                __hip_bfloat16* __restrict__ Qg,
                                                __hip_bfloat16* __restrict__ Kg,
                                                __hip_bfloat16* __restrict__ Vtg) {
    const int bf = blockIdx.z;            // b*2 + f01
    const int b = bf >> 1, f01 = bf & 1;
    const int jt = blockIdx.y;            // 0..11  (j block of 64)
    const int f_src = (jt < 4) ? f01 : (3 - f01);
    const int n0 = blockIdx.x * 64;
    const float* __restrict__ A = xs + (size_t)((b * 4 + f_src) * 64) * NPTS; // [c][n]

    __shared__ float As[64][68];   // [c][n] staged; reused as transpose bounce
    __shared__ float Ws[64][68];   // [j][c], padded stride

    const int t = threadIdx.x;
    const int tx = t & 15, ty = t >> 4;

    for (int r = 0; r < 4; ++r) {
        int row = ty + 16 * r;
        int col = tx * 4;
        *(float4*)&As[row][col] = *(const float4*)&A[(size_t)row * NPTS + n0 + col];
        *(float4*)&Ws[row][col] = *(const float4*)&Wp[(size_t)(jt * 64 + row) * 64 + col];
    }
    __syncthreads();

    // thread owns n = n0 + ty + 16i, j = jt*64 + tx + 16jj
    float acc[4][4];
#pragma unroll
    for (int jj = 0; jj < 4; ++jj) {
        float bv = bp[jt * 64 + tx + 16 * jj];
#pragma unroll
        for (int i = 0; i < 4; ++i) acc[i][jj] = bv;
    }
    for (int c = 0; c < 64; ++c) {
        float a[4], w[4];
#pragma unroll
        for (int i = 0; i < 4; ++i) a[i] = As[c][ty + 16 * i];
#pragma unroll
        for (int jj = 0; jj < 4; ++jj) w[jj] = Ws[tx + 16 * jj][c];
#pragma unroll
        for (int i = 0; i < 4; ++i)
#pragma unroll
            for (int jj = 0; jj < 4; ++jj) acc[i][jj] += a[i] * w[jj];
    }

    if (jt < 8) {
        __hip_bfloat16* __restrict__ dst = (jt < 4 ? Qg : Kg) + (size_t)bf * NPTS * 256;
        const int jb = (jt & 3) * 64;
#pragma unroll
        for (int i = 0; i < 4; ++i) {
            int n = n0 + ty + 16 * i;
#pragma unroll
            for (int jj = 0; jj < 4; ++jj)
                dst[(size_t)n * 256 + jb + tx + 16 * jj] = __float2bfloat16(acc[i][jj]);
        }
    } else {
        // V: transpose through LDS, write Vt[c][n] bf16 coalesced
        __syncthreads();
#pragma unroll
        for (int i = 0; i < 4; ++i)
#pragma unroll
            for (int jj = 0; jj < 4; ++jj)
                As[tx + 16 * jj][ty + 16 * i] = acc[i][jj];   // [j_local][n_local]
        __syncthreads();
        const int row = t >> 2, c0 = (t & 3) * 16;
        __hip_bfloat16* __restrict__ dst =
            Vtg + ((size_t)bf * 256 + (jt - 8) * 64 + row) * NPTS + n0 + c0;
#pragma unroll
        for (int c = 0; c < 16; ++c) dst[c] = __float2bfloat16(As[row][c0 + c]);
    }
}

// ---------------------------------------------------------------------------
// K2: MFMA flash attention, swapped-operand form (all P traffic in-register).
//   S^T = mfma(K_frag, Q_frag)  -> lane holds P^T[k][q], q = lane&15
//   pack exp2(S^T) via v_cvt_pk_bf16_f32, redistribute with
//   permlane32_swap + permlane16_swap into PV's B-fragment
//   O^T = mfma(V^T_frag, P^T_frag); unnormalized, l summed per lane.
// Grid (16 combo, 32 nblk, 2 ksplit): combo as x => same-combo blocks on one
// XCD (L2 locality); ksplit doubles occupancy (no-max softmax => partials add).
// ---------------------------------------------------------------------------
__global__ __launch_bounds__(256) void attn_mfma(const __hip_bfloat16* __restrict__ Qg,
                                                 const __hip_bfloat16* __restrict__ Kg,
                                                 const __hip_bfloat16* __restrict__ Vtg,
                                                 float* __restrict__ OT,
                                                 float* __restrict__ Lp) {
    const int combo = blockIdx.x;          // bf*4 + h
    const int bf = combo >> 2, h = combo & 3;
    const int n0 = blockIdx.y * 64;
    const int split = blockIdx.z;
    const int kbase = split * (NPTS / 2);
    const int NT = NPTS / 2 / 64;          // 16 k-tiles per split

    __shared__ __align__(16) char smem[32768];   // 2 x (K 8KB | Vt 8KB)

    const int t = threadIdx.x;
    const int lane = t & 63, w = t >> 6;
    const int l15 = lane & 15, g = lane >> 4;
    const int srow = lane >> 3, sslot = lane & 7;   // staging: 8 lanes per row

    // Q B-fragments straight from global: B[c = s*32 + g*8 + j][q=l15]
    const __hip_bfloat16* qbase =
        Qg + ((size_t)bf * NPTS + n0 + w * 16 + l15) * 256 + h * 64 + g * 8;
    bf16x8 qf0 = *(const bf16x8*)(qbase);
    bf16x8 qf1 = *(const bf16x8*)(qbase + 32);

    const __hip_bfloat16* kgb = Kg + (size_t)bf * NPTS * 256 + h * 64;
    const __hip_bfloat16* vgb = Vtg + ((size_t)bf * 256 + h * 64) * NPTS;

    f32x4 oacc[4];
    float lsum = 0.f;
#pragma unroll
    for (int r = 0; r < 4; ++r) oacc[r] = (f32x4){0.f, 0.f, 0.f, 0.f};

    auto stage = [&](int kt, int bsel) {
#pragma unroll
        for (int ii = 0; ii < 2; ++ii) {
            const int rb = w * 16 + ii * 8;
            const int r = rb + srow;
            const int cs = (sslot ^ (r & 7)) * 8;     // pre-swizzled source column
            const __hip_bfloat16* ksrc = kgb + (size_t)(kbase + kt * 64 + r) * 256 + cs;
            __builtin_amdgcn_global_load_lds((const glob_char*)ksrc,
                (lds_char*)(smem + bsel * 16384 + rb * 128), 16, 0, 0);
            const __hip_bfloat16* vsrc = vgb + (size_t)r * NPTS + kbase + kt * 64 + cs;
            __builtin_amdgcn_global_load_lds((const glob_char*)vsrc,
                (lds_char*)(smem + bsel * 16384 + 8192 + rb * 128), 16, 0, 0);
        }
    };

    stage(0, 0);
    int cur = 0;

    for (int kt = 0; kt < NT; ++kt) {
        if (kt < NT - 1) {
            stage(kt + 1, cur ^ 1);
            asm volatile("s_waitcnt vmcnt(4)" ::: "memory");
        } else {
            asm volatile("s_waitcnt vmcnt(0)" ::: "memory");
        }
        __builtin_amdgcn_s_barrier();
        asm volatile("" ::: "memory");

        char* const Kt = smem + cur * 16384;
        char* const Vt = Kt + 8192;

        // ---- S^T = K.Q^T per wave: lane holds S^T[k=tt*16+g*4+r][q=l15] ----
        f32x4 st[4];
#pragma unroll
        for (int tt = 0; tt < 4; ++tt) {
            const int row = tt * 16 + l15;
            bf16x8 kf0 = *(const bf16x8*)(Kt + row * 128 + ((g ^ (row & 7)) << 4));
            bf16x8 kf1 = *(const bf16x8*)(Kt + row * 128 + (((4 + g) ^ (row & 7)) << 4));
            f32x4 z = (f32x4){0.f, 0.f, 0.f, 0.f};
            z = __builtin_amdgcn_mfma_f32_16x16x32_bf16(kf0, qf0, z, 0, 0, 0);
            z = __builtin_amdgcn_mfma_f32_16x16x32_bf16(kf1, qf1, z, 0, 0, 0);
            st[tt] = z;
        }

        // ---- P = exp2(S); pack pairs to bf16; accumulate l (one q per lane) ----
        unsigned c0[4], c1[4];
#pragma unroll
        for (int tt = 0; tt < 4; ++tt) {
            float p0 = exp2f(fminf(st[tt][0], 126.f));
            float p1 = exp2f(fminf(st[tt][1], 126.f));
            float p2 = exp2f(fminf(st[tt][2], 126.f));
            float p3 = exp2f(fminf(st[tt][3], 126.f));
            lsum += (p0 + p1) + (p2 + p3);
            c0[tt] = cvt_pk_bf16(p0, p1);
            c1[tt] = cvt_pk_bf16(p2, p3);
        }

        // ---- redistribute P^T into PV B-fragments (2 swaps per word-pair) ----
        bf16x8 pb[2];
#pragma unroll
        for (int s = 0; s < 2; ++s) {
            unsigned x0 = c0[2 * s], y0 = c0[2 * s + 1];
            unsigned x1 = c1[2 * s], y1 = c1[2 * s + 1];
            asm("v_permlane32_swap_b32 %0, %1" : "+v"(x0), "+v"(y0));
            asm("v_permlane16_swap_b32 %0, %1" : "+v"(x0), "+v"(y0));
            asm("v_permlane32_swap_b32 %0, %1" : "+v"(x1), "+v"(y1));
            asm("v_permlane16_swap_b32 %0, %1" : "+v"(x1), "+v"(y1));
            PBU pu;
            pu.u = (uint32x4){x0, x1, y0, y1};
            pb[s] = pu.v;
        }

        // ---- O^T += V^T.P^T : lane holds O^T[c=ct*16+g*4+r][q=l15] ----
#pragma unroll
        for (int ct = 0; ct < 4; ++ct) {
            const int row = ct * 16 + l15;
            bf16x8 vf0 = *(const bf16x8*)(Vt + row * 128 + ((g ^ (row & 7)) << 4));
            bf16x8 vf1 = *(const bf16x8*)(Vt + row * 128 + (((4 + g) ^ (row & 7)) << 4));
            f32x4 z = oacc[ct];
            z = __builtin_amdgcn_mfma_f32_16x16x32_bf16(vf0, pb[0], z, 0, 0, 0);
            z = __builtin_amdgcn_mfma_f32_16x16x32_bf16(vf1, pb[1], z, 0, 0, 0);
            oacc[ct] = z;
        }

        asm volatile("s_waitcnt lgkmcnt(0)" ::: "memory");
        __builtin_amdgcn_s_barrier();
        asm volatile("" ::: "memory");
        cur ^= 1;
    }

    // l[q] = sum over the 4 lane groups holding distinct k for this q
    lsum += __shfl_xor(lsum, 16);
    lsum += __shfl_xor(lsum, 32);
    const int q = n0 + w * 16 + l15;
    if (g == 0)
        Lp[(size_t)(split * 16 + combo) * NPTS + q] = lsum;

    float* __restrict__ Op = OT + (size_t)(split * 16 + combo) * 64 * NPTS;
#pragma unroll
    for (int ct = 0; ct < 4; ++ct)
#pragma unroll
        for (int r = 0; r < 4; ++r)
            Op[(size_t)(ct * 16 + g * 4 + r) * NPTS + q] = oacc[ct][r];
}

// ---------------------------------------------------------------------------
// K3: combine attention partials + normalize, then
//     xa = (O_f0 + O_f1) @ proj_w.T + proj_b ; frames = xa @ map_w.T + map_b
// OT layout: [split*16+combo][c][n] unnormalized; l = Lp[0]+Lp[1] per (combo,n).
// ---------------------------------------------------------------------------
__global__ __launch_bounds__(256) void proj_frames(const float* __restrict__ OT,
                                                   const float* __restrict__ Lp,
                                                   const float* __restrict__ proj_w,
                                                   const float* __restrict__ proj_b,
                                                   const float* __restrict__ map_w,
                                                   const float* __restrict__ map_b,
                                                   float* __restrict__ out,
                                                   float* __restrict__ frames0) {
    const int bh = blockIdx.y, b = bh >> 2, h = bh & 3;
    const int n0 = blockIdx.x * 64;
    const int cf0 = (b * 2 + 0) * 4 + h;
    const int cf1 = (b * 2 + 1) * 4 + h;

    __shared__ float Xs[64][68];   // [c][n]
    __shared__ float Ws[64][68];   // [j][c]
    __shared__ float xaS[64][68];  // [n][j]

    const int t = threadIdx.x;
    const int tx = t & 15, ty = t >> 4;
    const int nc = n0 + tx * 4;

    // per-column 1/l for both frames
    float4 la = *(const float4*)&Lp[(size_t)cf0 * NPTS + nc];
    float4 lb = *(const float4*)&Lp[(size_t)(16 + cf0) * NPTS + nc];
    float4 inv0 = make_float4(1.f / (la.x + lb.x), 1.f / (la.y + lb.y),
                              1.f / (la.z + lb.z), 1.f / (la.w + lb.w));
    la = *(const float4*)&Lp[(size_t)cf1 * NPTS + nc];
    lb = *(const float4*)&Lp[(size_t)(16 + cf1) * NPTS + nc];
    float4 inv1 = make_float4(1.f / (la.x + lb.x), 1.f / (la.y + lb.y),
                              1.f / (la.z + lb.z), 1.f / (la.w + lb.w));

    for (int r = 0; r < 4; ++r) {
        int row = ty + 16 * r, col = tx * 4;   // row = c, col = n_local
        const float* p00 = OT + ((size_t)(cf0)      * 64 + row) * NPTS + n0 + col;
        const float* p01 = OT + ((size_t)(16 + cf0) * 64 + row) * NPTS + n0 + col;
        const float* p10 = OT + ((size_t)(cf1)      * 64 + row) * NPTS + n0 + col;
        const float* p11 = OT + ((size_t)(16 + cf1) * 64 + row) * NPTS + n0 + col;
        float4 a0 = *(const float4*)p00, a1 = *(const float4*)p01;
        float4 b0 = *(const float4*)p10, b1 = *(const float4*)p11;
        float4 x;
        x.x = (a0.x + a1.x) * inv0.x + (b0.x + b1.x) * inv1.x;
        x.y = (a0.y + a1.y) * inv0.y + (b0.y + b1.y) * inv1.y;
        x.z = (a0.z + a1.z) * inv0.z + (b0.z + b1.z) * inv1.z;
        x.w = (a0.w + a1.w) * inv0.w + (b0.w + b1.w) * inv1.w;
        *(float4*)&Xs[row][col] = x;
        *(float4*)&Ws[row][col] = *(const float4*)&proj_w[(size_t)row * 64 + col];
    }
    __syncthreads();

    float acc[4][4];
#pragma unroll
    for (int jj = 0; jj < 4; ++jj) {
        float bv = proj_b[tx + 16 * jj];
#pragma unroll
        for (int i = 0; i < 4; ++i) acc[i][jj] = bv;
    }
    for (int c = 0; c < 64; ++c) {
        float a[4], w[4];
#pragma unroll
        for (int i = 0; i < 4; ++i) a[i] = Xs[c][ty + 16 * i];
#pragma unroll
        for (int jj = 0; jj < 4; ++jj) w[jj] = Ws[tx + 16 * jj][c];
#pragma unroll
        for (int i = 0; i < 4; ++i)
#pragma unroll
            for (int jj = 0; jj < 4; ++jj) acc[i][jj] += a[i] * w[jj];
    }

#pragma unroll
    for (int i = 0; i < 4; ++i)
#pragma unroll
        for (int jj = 0; jj < 4; ++jj)
            xaS[ty + 16 * i][tx + 16 * jj] = acc[i][jj];

    if (h >= 1) {
        float* __restrict__ xa_out = out + (size_t)(b * 3 + h - 1) * NPTS * 64;
#pragma unroll
        for (int i = 0; i < 4; ++i)
#pragma unroll
            for (int jj = 0; jj < 4; ++jj)
                xa_out[(size_t)(n0 + ty + 16 * i) * 64 + tx + 16 * jj] = acc[i][jj];
    }
    __syncthreads();

    if (t < 192) {
        int r = t / 3, j = t % 3;
        float s = map_b[j];
        for (int c = 0; c < 64; ++c) s += xaS[r][c] * map_w[j * 64 + c];
        int n = n0 + r;
        if (h == 0) frames0[((size_t)b * NPTS + n) * 3 + j] = s;
        else        out[786432 + ((size_t)(b * 3 + h - 1) * NPTS + n) * 3 + j] = s;
    }
}

// ---------------------------------------------------------------------------
// K4a: chamfer partial mins.  grid (NPTS/256, NJC, 4); z = dir*2 + b.
// ---------------------------------------------------------------------------
__global__ __launch_bounds__(256) void chamfer_partial(const float* __restrict__ pc1,
                                                       const float* __restrict__ frames0,
                                                       float* __restrict__ partial) {
    const int z = blockIdx.z;          // dir*2 + b
    const int dir = z >> 1, b = z & 1;
    const int i = blockIdx.x * 256 + threadIdx.x;
    const int j0 = blockIdx.y * JCH;
    const float* __restrict__ px = pc1 + (size_t)b * 3 * NPTS;
    const float* __restrict__ fr = frames0 + (size_t)b * NPTS * 3;

    __shared__ float4 sj[JCH];
    if (threadIdx.x < JCH) {
        int jj = j0 + threadIdx.x;
        float bx = px[jj], by = px[NPTS + jj], bz = px[2 * NPTS + jj];
        if (dir == 1) { bx += fr[jj * 3]; by += fr[jj * 3 + 1]; bz += fr[jj * 3 + 2]; }
        sj[threadIdx.x] = make_float4(bx, by, bz, bx * bx + by * by + bz * bz);
    }
    float ax = px[i], ay = px[NPTS + i], az = px[2 * NPTS + i];
    if (dir == 0) { ax += fr[i * 3]; ay += fr[i * 3 + 1]; az += fr[i * 3 + 2]; }
    const float a2 = ax * ax + ay * ay + az * az;
    __syncthreads();

    float best = 1e30f;
#pragma unroll 4
    for (int k = 0; k < JCH; ++k) {
        float4 p = sj[k];
        float d = a2 + p.w - 2.0f * (ax * p.x + ay * p.y + az * p.z);
        best = fminf(best, d);
    }
    partial[((size_t)z * NJC + blockIdx.y) * NPTS + i] = best;
}

// ---------------------------------------------------------------------------
// K4b: min over chunks + per-block sum. 32 blocks x 256 thr; gid = z*2048 + i.
// ---------------------------------------------------------------------------
__global__ __launch_bounds__(256) void chamfer_minsum(const float* __restrict__ partial,
                                                      double* __restrict__ sums) {
    const int gid = blockIdx.x * 256 + threadIdx.x;
    const int z = gid >> 11, i = gid & 2047;
    float best = 1e30f;
#pragma unroll
    for (int c = 0; c < NJC; ++c)
        best = fminf(best, partial[((size_t)z * NJC + c) * NPTS + i]);
    __shared__ double sm[256];
    sm[threadIdx.x] = (double)best;
    __syncthreads();
    for (int off = 128; off > 0; off >>= 1) {
        if (threadIdx.x < off) sm[threadIdx.x] += sm[threadIdx.x + off];
        __syncthreads();
    }
    if (threadIdx.x == 0) sums[blockIdx.x] = sm[0];
}

__global__ void chamfer_final(const double* __restrict__ sums, float* __restrict__ loss_out) {
    if (threadIdx.x == 0) {
        double s = 0.0;
        for (int k = 0; k < 32; ++k) s += sums[k];
        loss_out[0] = (float)(s / 4096.0);
    }
}

// ---------------------------------------------------------------------------
extern "C" void kernel_launch(void* const* d_in, const int* in_sizes, int n_in,
                              void* d_out, int out_size, void* d_ws, size_t ws_size,
                              hipStream_t stream) {
    const float* xs     = (const float*)d_in[0];
    const float* pc1    = (const float*)d_in[1];
    // d_in[2] = pc2 (unused by reference)
    const float* gamma  = (const float*)d_in[3];
    const float* beta   = (const float*)d_in[4];
    const float* q_w    = (const float*)d_in[5];
    const float* kv_w   = (const float*)d_in[6];
    const float* proj_w = (const float*)d_in[7];
    const float* proj_b = (const float*)d_in[8];
    const float* map_w  = (const float*)d_in[9];
    const float* map_b  = (const float*)d_in[10];
    float* out = (float*)d_out;

    char* ws = (char*)d_ws;
    __hip_bfloat16* Qg  = (__hip_bfloat16*)(ws);              // 4 MiB
    __hip_bfloat16* Kg  = (__hip_bfloat16*)(ws + 4194304);    // 4 MiB
    __hip_bfloat16* Vtg = (__hip_bfloat16*)(ws + 8388608);    // 4 MiB
    float* OT      = (float*)(ws + 12582912);                 // 2*16*64*2048*4 = 16 MiB
    float* Wp      = (float*)(ws + 29360128);                 // 768*64*4
    float* bp      = (float*)(ws + 29556736);                 // 768*4
    float* frames0 = (float*)(ws + 29559808);                 // 2*2048*3*4
    float* partial = (float*)(ws + 29609984);                 // 4*16*2048*4 = 512 KiB
    double* sums   = (double*)(ws + 30134272);                // 32*8
    float* Lp      = (float*)(ws + 30134528);                 // 2*16*2048*4 = 256 KiB

    hipLaunchKernelGGL(prep_weights, dim3(3), dim3(256), 0, stream,
                       gamma, beta, q_w, kv_w, Wp, bp);
    hipLaunchKernelGGL(qkv_gemm, dim3(32, 12, 4), dim3(256), 0, stream,
                       xs, Wp, bp, Qg, Kg, Vtg);
    hipLaunchKernelGGL(attn_mfma, dim3(16, 32, 2), dim3(256), 0, stream,
                       Qg, Kg, Vtg, OT, Lp);
    hipLaunchKernelGGL(proj_frames, dim3(32, 8), dim3(256), 0, stream,
                       OT, Lp, proj_w, proj_b, map_w, map_b, out, frames0);
    hipLaunchKernelGGL(chamfer_partial, dim3(NPTS / 256, NJC, 4), dim3(256), 0, stream,
                       pc1, frames0, partial);
    hipLaunchKernelGGL(chamfer_minsum, dim3(32), dim3(256), 0, stream,
                       partial, sums);
    hipLaunchKernelGGL(chamfer_final, dim3(1), dim3(64), 0, stream,
                       sums, out + 823296);
}

// Round 5
// 91.860 us; speedup vs baseline: 9.5271x; 1.0119x over previous
//
#include <hip/hip_runtime.h>
#include <hip/hip_bf16.h>

#define NPTS 2048
#define LOG2E 1.4426950408889634f
#define NJC 16     // chamfer j-chunks
#define JCH 128    // points per chunk

typedef short bf16x8 __attribute__((ext_vector_type(8)));
typedef float f32x4 __attribute__((ext_vector_type(4)));
typedef unsigned uint32x4 __attribute__((ext_vector_type(4)));
typedef __attribute__((address_space(3))) char lds_char;
typedef __attribute__((address_space(1))) const char glob_char;

union PBU { uint32x4 u; bf16x8 v; };

static __device__ __forceinline__ unsigned cvt_pk_bf16(float a, float b) {
    unsigned r;
    asm("v_cvt_pk_bf16_f32 %0, %1, %2" : "=v"(r) : "v"(a), "v"(b));
    return r;
}
static __device__ __forceinline__ float b2f(unsigned short u) {
    return __uint_as_float((unsigned)u << 16);
}

// ---------------------------------------------------------------------------
// K0: fold BN affine + softmax scale + log2e into combined QKV weights.
// ---------------------------------------------------------------------------
__global__ void prep_weights(const float* __restrict__ gamma, const float* __restrict__ beta,
                             const float* __restrict__ q_w, const float* __restrict__ kv_w,
                             float* __restrict__ Wp, float* __restrict__ bp) {
    int j = blockIdx.x * blockDim.x + threadIdx.x;
    if (j >= 768) return;
    const float inv = 1.0f / sqrtf(1.0f + 1e-5f);
    const float* src;
    float scale;
    if (j < 256) { src = q_w + j * 64;          scale = 0.125f * LOG2E; }
    else         { src = kv_w + (j - 256) * 64; scale = 1.0f; }
    float b = 0.f;
    for (int c = 0; c < 64; ++c) {
        float w = src[c];
        Wp[j * 64 + c] = w * gamma[c] * inv * scale;
        b += w * beta[c];
    }
    bp[j] = b * scale;
}

// ---------------------------------------------------------------------------
// K1: QKV GEMM.  Emits bf16 Qg/Kg [bf][n][256] and transposed bf16 Vt [bf][256][n].
// ---------------------------------------------------------------------------
__global__ __launch_bounds__(256) void qkv_gemm(const float* __restrict__ xs,
                                                const float* __restrict__ Wp,
                                                const float* __restrict__ bp,
                                                __hip_bfloat16* __restrict__ Qg,
                                                __hip_bfloat16* __restrict__ Kg,
                                                __hip_bfloat16* __restrict__ Vtg) {
    const int bf = blockIdx.z;            // b*2 + f01
    const int b = bf >> 1, f01 = bf & 1;
    const int jt = blockIdx.y;            // 0..11  (j block of 64)
    const int f_src = (jt < 4) ? f01 : (3 - f01);
    const int n0 = blockIdx.x * 64;
    const float* __restrict__ A = xs + (size_t)((b * 4 + f_src) * 64) * NPTS; // [c][n]

    __shared__ float As[64][68];   // [c][n] staged; reused as transpose bounce
    __shared__ float Ws[64][68];   // [j][c], padded stride

    const int t = threadIdx.x;
    const int tx = t & 15, ty = t >> 4;

    for (int r = 0; r < 4; ++r) {
        int row = ty + 16 * r;
        int col = tx * 4;
        *(float4*)&As[row][col] = *(const float4*)&A[(size_t)row * NPTS + n0 + col];
        *(float4*)&Ws[row][col] = *(const float4*)&Wp[(size_t)(jt * 64 + row) * 64 + col];
    }
    __syncthreads();

    float acc[4][4];
#pragma unroll
    for (int jj = 0; jj < 4; ++jj) {
        float bv = bp[jt * 64 + tx + 16 * jj];
#pragma unroll
        for (int i = 0; i < 4; ++i) acc[i][jj] = bv;
    }
    for (int c = 0; c < 64; ++c) {
        float a[4], w[4];
#pragma unroll
        for (int i = 0; i < 4; ++i) a[i] = As[c][ty + 16 * i];
#pragma unroll
        for (int jj = 0; jj < 4; ++jj) w[jj] = Ws[tx + 16 * jj][c];
#pragma unroll
        for (int i = 0; i < 4; ++i)
#pragma unroll
            for (int jj = 0; jj < 4; ++jj) acc[i][jj] += a[i] * w[jj];
    }

    if (jt < 8) {
        __hip_bfloat16* __restrict__ dst = (jt < 4 ? Qg : Kg) + (size_t)bf * NPTS * 256;
        const int jb = (jt & 3) * 64;
#pragma unroll
        for (int i = 0; i < 4; ++i) {
            int n = n0 + ty + 16 * i;
#pragma unroll
            for (int jj = 0; jj < 4; ++jj)
                dst[(size_t)n * 256 + jb + tx + 16 * jj] = __float2bfloat16(acc[i][jj]);
        }
    } else {
        // V: transpose through LDS, write Vt[c][n] bf16 coalesced
        __syncthreads();
#pragma unroll
        for (int i = 0; i < 4; ++i)
#pragma unroll
            for (int jj = 0; jj < 4; ++jj)
                As[tx + 16 * jj][ty + 16 * i] = acc[i][jj];   // [j_local][n_local]
        __syncthreads();
        const int row = t >> 2, c0 = (t & 3) * 16;
        __hip_bfloat16* __restrict__ dst =
            Vtg + ((size_t)bf * 256 + (jt - 8) * 64 + row) * NPTS + n0 + c0;
#pragma unroll
        for (int c = 0; c < 16; ++c) dst[c] = __float2bfloat16(As[row][c0 + c]);
    }
}

// ---------------------------------------------------------------------------
// K2: MFMA flash attention, swapped-operand, 32 q rows per wave (2 q-frags).
// Each 64-k tile: 8 K-reads + 8 V-reads feed 32 MFMAs (2x work per LDS byte).
// Grid (16 combo, 16 nblk, 4 ksplit): same-combo blocks share one XCD.
// Partial O^T stored bf16; l partial f32; combined in proj_frames.
// ---------------------------------------------------------------------------
__global__ __launch_bounds__(256, 4) void attn_mfma(const __hip_bfloat16* __restrict__ Qg,
                                                    const __hip_bfloat16* __restrict__ Kg,
                                                    const __hip_bfloat16* __restrict__ Vtg,
                                                    __hip_bfloat16* __restrict__ OTb,
                                                    float* __restrict__ Lp) {
    const int combo = blockIdx.x;          // bf*4 + h
    const int bf = combo >> 2, h = combo & 3;
    const int n0 = blockIdx.y * 128;
    const int split = blockIdx.z;
    const int kbase = split * (NPTS / 4);
    const int NT = NPTS / 4 / 64;          // 8 k-tiles per split

    __shared__ __align__(16) char smem[32768];   // 2 x (K 8KB | Vt 8KB)

    const int t = threadIdx.x;
    const int lane = t & 63, w = t >> 6;
    const int l15 = lane & 15, g = lane >> 4;
    const int srow = lane >> 3, sslot = lane & 7;   // staging: 8 lanes per row

    // Q B-fragments: frag f covers q rows n0 + w*32 + f*16 + l15
    const __hip_bfloat16* qbase =
        Qg + ((size_t)bf * NPTS + n0 + w * 32 + l15) * 256 + h * 64 + g * 8;
    bf16x8 qf[2][2];
    qf[0][0] = *(const bf16x8*)(qbase);
    qf[0][1] = *(const bf16x8*)(qbase + 32);
    qf[1][0] = *(const bf16x8*)(qbase + 16 * 256);
    qf[1][1] = *(const bf16x8*)(qbase + 16 * 256 + 32);

    const __hip_bfloat16* kgb = Kg + (size_t)bf * NPTS * 256 + h * 64;
    const __hip_bfloat16* vgb = Vtg + ((size_t)bf * 256 + h * 64) * NPTS;

    // hoisted LDS byte offsets (K; V = same + 8192)
    int ldsoff[4][2];
#pragma unroll
    for (int tt = 0; tt < 4; ++tt) {
        const int row = tt * 16 + l15;
#pragma unroll
        for (int s = 0; s < 2; ++s)
            ldsoff[tt][s] = row * 128 + (((s * 4 + g) ^ (row & 7)) << 4);
    }

    f32x4 oacc[2][4];
    float lsum0 = 0.f, lsum1 = 0.f;
#pragma unroll
    for (int f = 0; f < 2; ++f)
#pragma unroll
        for (int r = 0; r < 4; ++r) oacc[f][r] = (f32x4){0.f, 0.f, 0.f, 0.f};

    auto stage = [&](int kt, int bsel) {
#pragma unroll
        for (int ii = 0; ii < 2; ++ii) {
            const int rb = w * 16 + ii * 8;
            const int r = rb + srow;
            const int cs = (sslot ^ (r & 7)) * 8;     // pre-swizzled source column
            const __hip_bfloat16* ksrc = kgb + (size_t)(kbase + kt * 64 + r) * 256 + cs;
            __builtin_amdgcn_global_load_lds((const glob_char*)ksrc,
                (lds_char*)(smem + bsel * 16384 + rb * 128), 16, 0, 0);
            const __hip_bfloat16* vsrc = vgb + (size_t)r * NPTS + kbase + kt * 64 + cs;
            __builtin_amdgcn_global_load_lds((const glob_char*)vsrc,
                (lds_char*)(smem + bsel * 16384 + 8192 + rb * 128), 16, 0, 0);
        }
    };

    stage(0, 0);
    int cur = 0;

    for (int kt = 0; kt < NT; ++kt) {
        if (kt < NT - 1) {
            stage(kt + 1, cur ^ 1);
            asm volatile("s_waitcnt vmcnt(4)" ::: "memory");
        } else {
            asm volatile("s_waitcnt vmcnt(0)" ::: "memory");
        }
        __builtin_amdgcn_s_barrier();
        asm volatile("" ::: "memory");

        const char* Kt = smem + cur * 16384;
        const char* Vt = Kt + 8192;

        // ---- read K fragments once, reuse for both q-frags ----
        bf16x8 kf[4][2];
#pragma unroll
        for (int tt = 0; tt < 4; ++tt) {
            kf[tt][0] = *(const bf16x8*)(Kt + ldsoff[tt][0]);
            kf[tt][1] = *(const bf16x8*)(Kt + ldsoff[tt][1]);
        }

        bf16x8 pb0[2], pb1[2];

        // ---- frag 0: S^T, softmax, pack ----
        {
            f32x4 st[4];
            __builtin_amdgcn_s_setprio(1);
#pragma unroll
            for (int tt = 0; tt < 4; ++tt) {
                f32x4 z = (f32x4){0.f, 0.f, 0.f, 0.f};
                z = __builtin_amdgcn_mfma_f32_16x16x32_bf16(kf[tt][0], qf[0][0], z, 0, 0, 0);
                z = __builtin_amdgcn_mfma_f32_16x16x32_bf16(kf[tt][1], qf[0][1], z, 0, 0, 0);
                st[tt] = z;
            }
            __builtin_amdgcn_s_setprio(0);
            unsigned c0[4], c1[4];
#pragma unroll
            for (int tt = 0; tt < 4; ++tt) {
                float p0 = exp2f(fminf(st[tt][0], 126.f));
                float p1 = exp2f(fminf(st[tt][1], 126.f));
                float p2 = exp2f(fminf(st[tt][2], 126.f));
                float p3 = exp2f(fminf(st[tt][3], 126.f));
                lsum0 += (p0 + p1) + (p2 + p3);
                c0[tt] = cvt_pk_bf16(p0, p1);
                c1[tt] = cvt_pk_bf16(p2, p3);
            }
#pragma unroll
            for (int s = 0; s < 2; ++s) {
                unsigned x0 = c0[2 * s], y0 = c0[2 * s + 1];
                unsigned x1 = c1[2 * s], y1 = c1[2 * s + 1];
                asm("v_permlane32_swap_b32 %0, %1" : "+v"(x0), "+v"(y0));
                asm("v_permlane16_swap_b32 %0, %1" : "+v"(x0), "+v"(y0));
                asm("v_permlane32_swap_b32 %0, %1" : "+v"(x1), "+v"(y1));
                asm("v_permlane16_swap_b32 %0, %1" : "+v"(x1), "+v"(y1));
                PBU pu;
                pu.u = (uint32x4){x0, x1, y0, y1};
                pb0[s] = pu.v;
            }
        }

        // ---- frag 1: S^T, softmax, pack ----
        {
            f32x4 st[4];
            __builtin_amdgcn_s_setprio(1);
#pragma unroll
            for (int tt = 0; tt < 4; ++tt) {
                f32x4 z = (f32x4){0.f, 0.f, 0.f, 0.f};
                z = __builtin_amdgcn_mfma_f32_16x16x32_bf16(kf[tt][0], qf[1][0], z, 0, 0, 0);
                z = __builtin_amdgcn_mfma_f32_16x16x32_bf16(kf[tt][1], qf[1][1], z, 0, 0, 0);
                st[tt] = z;
            }
            __builtin_amdgcn_s_setprio(0);
            unsigned c0[4], c1[4];
#pragma unroll
            for (int tt = 0; tt < 4; ++tt) {
                float p0 = exp2f(fminf(st[tt][0], 126.f));
                float p1 = exp2f(fminf(st[tt][1], 126.f));
                float p2 = exp2f(fminf(st[tt][2], 126.f));
                float p3 = exp2f(fminf(st[tt][3], 126.f));
                lsum1 += (p0 + p1) + (p2 + p3);
                c0[tt] = cvt_pk_bf16(p0, p1);
                c1[tt] = cvt_pk_bf16(p2, p3);
            }
#pragma unroll
            for (int s = 0; s < 2; ++s) {
                unsigned x0 = c0[2 * s], y0 = c0[2 * s + 1];
                unsigned x1 = c1[2 * s], y1 = c1[2 * s + 1];
                asm("v_permlane32_swap_b32 %0, %1" : "+v"(x0), "+v"(y0));
                asm("v_permlane16_swap_b32 %0, %1" : "+v"(x0), "+v"(y0));
                asm("v_permlane32_swap_b32 %0, %1" : "+v"(x1), "+v"(y1));
                asm("v_permlane16_swap_b32 %0, %1" : "+v"(x1), "+v"(y1));
                PBU pu;
                pu.u = (uint32x4){x0, x1, y0, y1};
                pb1[s] = pu.v;
            }
        }

        // ---- PV: V fragments read once, feed both q-frags ----
        __builtin_amdgcn_s_setprio(1);
#pragma unroll
        for (int ct = 0; ct < 4; ++ct) {
            bf16x8 vf0 = *(const bf16x8*)(Vt + ldsoff[ct][0]);
            bf16x8 vf1 = *(const bf16x8*)(Vt + ldsoff[ct][1]);
            f32x4 z0 = oacc[0][ct];
            z0 = __builtin_amdgcn_mfma_f32_16x16x32_bf16(vf0, pb0[0], z0, 0, 0, 0);
            z0 = __builtin_amdgcn_mfma_f32_16x16x32_bf16(vf1, pb0[1], z0, 0, 0, 0);
            oacc[0][ct] = z0;
            f32x4 z1 = oacc[1][ct];
            z1 = __builtin_amdgcn_mfma_f32_16x16x32_bf16(vf0, pb1[0], z1, 0, 0, 0);
            z1 = __builtin_amdgcn_mfma_f32_16x16x32_bf16(vf1, pb1[1], z1, 0, 0, 0);
            oacc[1][ct] = z1;
        }
        __builtin_amdgcn_s_setprio(0);

        asm volatile("s_waitcnt lgkmcnt(0)" ::: "memory");
        __builtin_amdgcn_s_barrier();
        asm volatile("" ::: "memory");
        cur ^= 1;
    }

    // l[q]: sum over the 4 lane groups holding distinct k for each q
    lsum0 += __shfl_xor(lsum0, 16);
    lsum0 += __shfl_xor(lsum0, 32);
    lsum1 += __shfl_xor(lsum1, 16);
    lsum1 += __shfl_xor(lsum1, 32);
    const int qq = n0 + w * 32 + l15;
    if (g == 0) {
        Lp[(size_t)(split * 16 + combo) * NPTS + qq] = lsum0;
        Lp[(size_t)(split * 16 + combo) * NPTS + qq + 16] = lsum1;
    }

    __hip_bfloat16* __restrict__ Op = OTb + (size_t)(split * 16 + combo) * 64 * NPTS;
#pragma unroll
    for (int ct = 0; ct < 4; ++ct)
#pragma unroll
        for (int r = 0; r < 4; ++r) {
            Op[(size_t)(ct * 16 + g * 4 + r) * NPTS + qq] = __float2bfloat16(oacc[0][ct][r]);
            Op[(size_t)(ct * 16 + g * 4 + r) * NPTS + qq + 16] = __float2bfloat16(oacc[1][ct][r]);
        }
}

// ---------------------------------------------------------------------------
// K3: combine 4 attention partials + normalize, then
//     xa = (O_f0 + O_f1) @ proj_w.T + proj_b ; frames = xa @ map_w.T + map_b
// ---------------------------------------------------------------------------
__global__ __launch_bounds__(256) void proj_frames(const __hip_bfloat16* __restrict__ OTb,
                                                   const float* __restrict__ Lp,
                                                   const float* __restrict__ proj_w,
                                                   const float* __restrict__ proj_b,
                                                   const float* __restrict__ map_w,
                                                   const float* __restrict__ map_b,
                                                   float* __restrict__ out,
                                                   float* __restrict__ frames0) {
    const int bh = blockIdx.y, b = bh >> 2, h = bh & 3;
    const int n0 = blockIdx.x * 64;
    const int cf0 = (b * 2 + 0) * 4 + h;
    const int cf1 = (b * 2 + 1) * 4 + h;

    __shared__ float Xs[64][68];   // [c][n]
    __shared__ float Ws[64][68];   // [j][c]
    __shared__ float xaS[64][68];  // [n][j]

    const int t = threadIdx.x;
    const int tx = t & 15, ty = t >> 4;
    const int nc = n0 + tx * 4;

    float4 L0 = make_float4(0.f, 0.f, 0.f, 0.f), L1 = L0;
#pragma unroll
    for (int s = 0; s < 4; ++s) {
        float4 a = *(const float4*)&Lp[(size_t)(s * 16 + cf0) * NPTS + nc];
        L0.x += a.x; L0.y += a.y; L0.z += a.z; L0.w += a.w;
        float4 c = *(const float4*)&Lp[(size_t)(s * 16 + cf1) * NPTS + nc];
        L1.x += c.x; L1.y += c.y; L1.z += c.z; L1.w += c.w;
    }
    float4 inv0 = make_float4(1.f / L0.x, 1.f / L0.y, 1.f / L0.z, 1.f / L0.w);
    float4 inv1 = make_float4(1.f / L1.x, 1.f / L1.y, 1.f / L1.z, 1.f / L1.w);

    for (int r = 0; r < 4; ++r) {
        int row = ty + 16 * r, col = tx * 4;   // row = c, col = n_local
        float x0 = 0.f, x1 = 0.f, x2 = 0.f, x3 = 0.f;
        float y0 = 0.f, y1 = 0.f, y2 = 0.f, y3 = 0.f;
#pragma unroll
        for (int s = 0; s < 4; ++s) {
            ushort4 u0 = *(const ushort4*)&OTb[((size_t)(s * 16 + cf0) * 64 + row) * NPTS + n0 + col];
            ushort4 u1 = *(const ushort4*)&OTb[((size_t)(s * 16 + cf1) * 64 + row) * NPTS + n0 + col];
            x0 += b2f(u0.x); x1 += b2f(u0.y); x2 += b2f(u0.z); x3 += b2f(u0.w);
            y0 += b2f(u1.x); y1 += b2f(u1.y); y2 += b2f(u1.z); y3 += b2f(u1.w);
        }
        Xs[row][col + 0] = x0 * inv0.x + y0 * inv1.x;
        Xs[row][col + 1] = x1 * inv0.y + y1 * inv1.y;
        Xs[row][col + 2] = x2 * inv0.z + y2 * inv1.z;
        Xs[row][col + 3] = x3 * inv0.w + y3 * inv1.w;
        *(float4*)&Ws[row][col] = *(const float4*)&proj_w[(size_t)row * 64 + col];
    }
    __syncthreads();

    float acc[4][4];
#pragma unroll
    for (int jj = 0; jj < 4; ++jj) {
        float bv = proj_b[tx + 16 * jj];
#pragma unroll
        for (int i = 0; i < 4; ++i) acc[i][jj] = bv;
    }
    for (int c = 0; c < 64; ++c) {
        float a[4], w[4];
#pragma unroll
        for (int i = 0; i < 4; ++i) a[i] = Xs[c][ty + 16 * i];
#pragma unroll
        for (int jj = 0; jj < 4; ++jj) w[jj] = Ws[tx + 16 * jj][c];
#pragma unroll
        for (int i = 0; i < 4; ++i)
#pragma unroll
            for (int jj = 0; jj < 4; ++jj) acc[i][jj] += a[i] * w[jj];
    }

#pragma unroll
    for (int i = 0; i < 4; ++i)
#pragma unroll
        for (int jj = 0; jj < 4; ++jj)
            xaS[ty + 16 * i][tx + 16 * jj] = acc[i][jj];

    if (h >= 1) {
        float* __restrict__ xa_out = out + (size_t)(b * 3 + h - 1) * NPTS * 64;
#pragma unroll
        for (int i = 0; i < 4; ++i)
#pragma unroll
            for (int jj = 0; jj < 4; ++jj)
                xa_out[(size_t)(n0 + ty + 16 * i) * 64 + tx + 16 * jj] = acc[i][jj];
    }
    __syncthreads();

    if (t < 192) {
        int r = t / 3, j = t % 3;
        float s = map_b[j];
        for (int c = 0; c < 64; ++c) s += xaS[r][c] * map_w[j * 64 + c];
        int n = n0 + r;
        if (h == 0) frames0[((size_t)b * NPTS + n) * 3 + j] = s;
        else        out[786432 + ((size_t)(b * 3 + h - 1) * NPTS + n) * 3 + j] = s;
    }
}

// ---------------------------------------------------------------------------
// K4a: chamfer partial mins.  grid (NPTS/256, NJC, 4); z = dir*2 + b.
// ---------------------------------------------------------------------------
__global__ __launch_bounds__(256) void chamfer_partial(const float* __restrict__ pc1,
                                                       const float* __restrict__ frames0,
                                                       float* __restrict__ partial) {
    const int z = blockIdx.z;          // dir*2 + b
    const int dir = z >> 1, b = z & 1;
    const int i = blockIdx.x * 256 + threadIdx.x;
    const int j0 = blockIdx.y * JCH;
    const float* __restrict__ px = pc1 + (size_t)b * 3 * NPTS;
    const float* __restrict__ fr = frames0 + (size_t)b * NPTS * 3;

    __shared__ float4 sj[JCH];
    if (threadIdx.x < JCH) {
        int jj = j0 + threadIdx.x;
        float bx = px[jj], by = px[NPTS + jj], bz = px[2 * NPTS + jj];
        if (dir == 1) { bx += fr[jj * 3]; by += fr[jj * 3 + 1]; bz += fr[jj * 3 + 2]; }
        sj[threadIdx.x] = make_float4(bx, by, bz, bx * bx + by * by + bz * bz);
    }
    float ax = px[i], ay = px[NPTS + i], az = px[2 * NPTS + i];
    if (dir == 0) { ax += fr[i * 3]; ay += fr[i * 3 + 1]; az += fr[i * 3 + 2]; }
    const float a2 = ax * ax + ay * ay + az * az;
    __syncthreads();

    float best = 1e30f;
#pragma unroll 4
    for (int k = 0; k < JCH; ++k) {
        float4 p = sj[k];
        float d = a2 + p.w - 2.0f * (ax * p.x + ay * p.y + az * p.z);
        best = fminf(best, d);
    }
    partial[((size_t)z * NJC + blockIdx.y) * NPTS + i] = best;
}

// ---------------------------------------------------------------------------
// K4b: min over chunks + per-block sum. 32 blocks x 256 thr.
// ---------------------------------------------------------------------------
__global__ __launch_bounds__(256) void chamfer_minsum(const float* __restrict__ partial,
                                                      double* __restrict__ sums) {
    const int gid = blockIdx.x * 256 + threadIdx.x;
    const int z = gid >> 11, i = gid & 2047;
    float best = 1e30f;
#pragma unroll
    for (int c = 0; c < NJC; ++c)
        best = fminf(best, partial[((size_t)z * NJC + c) * NPTS + i]);
    __shared__ double sm[256];
    sm[threadIdx.x] = (double)best;
    __syncthreads();
    for (int off = 128; off > 0; off >>= 1) {
        if (threadIdx.x < off) sm[threadIdx.x] += sm[threadIdx.x + off];
        __syncthreads();
    }
    if (threadIdx.x == 0) sums[blockIdx.x] = sm[0];
}

__global__ void chamfer_final(const double* __restrict__ sums, float* __restrict__ loss_out) {
    if (threadIdx.x == 0) {
        double s = 0.0;
        for (int k = 0; k < 32; ++k) s += sums[k];
        loss_out[0] = (float)(s / 4096.0);
    }
}

// ---------------------------------------------------------------------------
extern "C" void kernel_launch(void* const* d_in, const int* in_sizes, int n_in,
                              void* d_out, int out_size, void* d_ws, size_t ws_size,
                              hipStream_t stream) {
    const float* xs     = (const float*)d_in[0];
    const float* pc1    = (const float*)d_in[1];
    // d_in[2] = pc2 (unused by reference)
    const float* gamma  = (const float*)d_in[3];
    const float* beta   = (const float*)d_in[4];
    const float* q_w    = (const float*)d_in[5];
    const float* kv_w   = (const float*)d_in[6];
    const float* proj_w = (const float*)d_in[7];
    const float* proj_b = (const float*)d_in[8];
    const float* map_w  = (const float*)d_in[9];
    const float* map_b  = (const float*)d_in[10];
    float* out = (float*)d_out;

    char* ws = (char*)d_ws;
    __hip_bfloat16* Qg  = (__hip_bfloat16*)(ws);              // 4 MiB
    __hip_bfloat16* Kg  = (__hip_bfloat16*)(ws + 4194304);    // 4 MiB
    __hip_bfloat16* Vtg = (__hip_bfloat16*)(ws + 8388608);    // 4 MiB
    __hip_bfloat16* OTb = (__hip_bfloat16*)(ws + 12582912);   // 4*16*64*2048*2 = 16 MiB
    float* Wp      = (float*)(ws + 29360128);                 // 768*64*4
    float* bp      = (float*)(ws + 29556736);                 // 768*4
    float* frames0 = (float*)(ws + 29559808);                 // 2*2048*3*4
    float* partial = (float*)(ws + 29609984);                 // 512 KiB
    double* sums   = (double*)(ws + 30134272);                // 32*8
    float* Lp      = (float*)(ws + 30134528);                 // 4*16*2048*4 = 512 KiB

    hipLaunchKernelGGL(prep_weights, dim3(3), dim3(256), 0, stream,
                       gamma, beta, q_w, kv_w, Wp, bp);
    hipLaunchKernelGGL(qkv_gemm, dim3(32, 12, 4), dim3(256), 0, stream,
                       xs, Wp, bp, Qg, Kg, Vtg);
    hipLaunchKernelGGL(attn_mfma, dim3(16, 16, 4), dim3(256), 0, stream,
                       Qg, Kg, Vtg, OTb, Lp);
    hipLaunchKernelGGL(proj_frames, dim3(32, 8), dim3(256), 0, stream,
                       OTb, Lp, proj_w, proj_b, map_w, map_b, out, frames0);
    hipLaunchKernelGGL(chamfer_partial, dim3(NPTS / 256, NJC, 4), dim3(256), 0, stream,
                       pc1, frames0, partial);
    hipLaunchKernelGGL(chamfer_minsum, dim3(32), dim3(256), 0, stream,
                       partial, sums);
    hipLaunchKernelGGL(chamfer_final, dim3(1), dim3(64), 0, stream,
                       sums, out + 823296);
}

// Round 7
// 89.252 us; speedup vs baseline: 9.8054x; 1.0292x over previous
//
#include <hip/hip_runtime.h>
#include <hip/hip_bf16.h>

#define NPTS 2048
#define LOG2E 1.4426950408889634f
#define NJC 16     // chamfer j-chunks
#define JCH 128    // points per chunk

typedef short bf16x8 __attribute__((ext_vector_type(8)));
typedef float f32x4 __attribute__((ext_vector_type(4)));
typedef unsigned uint32x4 __attribute__((ext_vector_type(4)));
typedef __attribute__((address_space(3))) char lds_char;
typedef __attribute__((address_space(1))) const char glob_char;

union PBU { uint32x4 u; bf16x8 v; };

static __device__ __forceinline__ unsigned cvt_pk_bf16(float a, float b) {
    unsigned r;
    asm("v_cvt_pk_bf16_f32 %0, %1, %2" : "=v"(r) : "v"(a), "v"(b));
    return r;
}
static __device__ __forceinline__ float b2f(unsigned short u) {
    return __uint_as_float((unsigned)u << 16);
}

// ---------------------------------------------------------------------------
// K0: fold BN affine + softmax scale + log2e into combined QKV weights.
// ---------------------------------------------------------------------------
__global__ void prep_weights(const float* __restrict__ gamma, const float* __restrict__ beta,
                             const float* __restrict__ q_w, const float* __restrict__ kv_w,
                             float* __restrict__ Wp, float* __restrict__ bp) {
    int j = blockIdx.x * blockDim.x + threadIdx.x;
    if (j >= 768) return;
    const float inv = 1.0f / sqrtf(1.0f + 1e-5f);
    const float* src;
    float scale;
    if (j < 256) { src = q_w + j * 64;          scale = 0.125f * LOG2E; }
    else         { src = kv_w + (j - 256) * 64; scale = 1.0f; }
    float b = 0.f;
    for (int c = 0; c < 64; ++c) {
        float w = src[c];
        Wp[j * 64 + c] = w * gamma[c] * inv * scale;
        b += w * beta[c];
    }
    bp[j] = b * scale;
}

// ---------------------------------------------------------------------------
// K1: QKV GEMM.  Emits bf16 Qg/Kg [bf][n][256] and transposed bf16 Vt [bf][256][n].
// ---------------------------------------------------------------------------
__global__ __launch_bounds__(256) void qkv_gemm(const float* __restrict__ xs,
                                                const float* __restrict__ Wp,
                                                const float* __restrict__ bp,
                                                __hip_bfloat16* __restrict__ Qg,
                                                __hip_bfloat16* __restrict__ Kg,
                                                __hip_bfloat16* __restrict__ Vtg) {
    const int bf = blockIdx.z;            // b*2 + f01
    const int b = bf >> 1, f01 = bf & 1;
    const int jt = blockIdx.y;            // 0..11  (j block of 64)
    const int f_src = (jt < 4) ? f01 : (3 - f01);
    const int n0 = blockIdx.x * 64;
    const float* __restrict__ A = xs + (size_t)((b * 4 + f_src) * 64) * NPTS; // [c][n]

    __shared__ float As[64][68];   // [c][n] staged; reused as transpose bounce
    __shared__ float Ws[64][68];   // [j][c], padded stride

    const int t = threadIdx.x;
    const int tx = t & 15, ty = t >> 4;

    for (int r = 0; r < 4; ++r) {
        int row = ty + 16 * r;
        int col = tx * 4;
        *(float4*)&As[row][col] = *(const float4*)&A[(size_t)row * NPTS + n0 + col];
        *(float4*)&Ws[row][col] = *(const float4*)&Wp[(size_t)(jt * 64 + row) * 64 + col];
    }
    __syncthreads();

    float acc[4][4];
#pragma unroll
    for (int jj = 0; jj < 4; ++jj) {
        float bv = bp[jt * 64 + tx + 16 * jj];
#pragma unroll
        for (int i = 0; i < 4; ++i) acc[i][jj] = bv;
    }
    for (int c = 0; c < 64; ++c) {
        float a[4], w[4];
#pragma unroll
        for (int i = 0; i < 4; ++i) a[i] = As[c][ty + 16 * i];
#pragma unroll
        for (int jj = 0; jj < 4; ++jj) w[jj] = Ws[tx + 16 * jj][c];
#pragma unroll
        for (int i = 0; i < 4; ++i)
#pragma unroll
            for (int jj = 0; jj < 4; ++jj) acc[i][jj] += a[i] * w[jj];
    }

    if (jt < 8) {
        __hip_bfloat16* __restrict__ dst = (jt < 4 ? Qg : Kg) + (size_t)bf * NPTS * 256;
        const int jb = (jt & 3) * 64;
#pragma unroll
        for (int i = 0; i < 4; ++i) {
            int n = n0 + ty + 16 * i;
#pragma unroll
            for (int jj = 0; jj < 4; ++jj)
                dst[(size_t)n * 256 + jb + tx + 16 * jj] = __float2bfloat16(acc[i][jj]);
        }
    } else {
        // V: transpose through LDS, write Vt[c][n] bf16 coalesced
        __syncthreads();
#pragma unroll
        for (int i = 0; i < 4; ++i)
#pragma unroll
            for (int jj = 0; jj < 4; ++jj)
                As[tx + 16 * jj][ty + 16 * i] = acc[i][jj];   // [j_local][n_local]
        __syncthreads();
        const int row = t >> 2, c0 = (t & 3) * 16;
        __hip_bfloat16* __restrict__ dst =
            Vtg + ((size_t)bf * 256 + (jt - 8) * 64 + row) * NPTS + n0 + c0;
#pragma unroll
        for (int c = 0; c < 16; ++c) dst[c] = __float2bfloat16(As[row][c0 + c]);
    }
}

// ---------------------------------------------------------------------------
// K2: MFMA flash attention, swapped-operand, 32 q/wave, 32-k tiles,
// QUAD-buffered LDS (4 x 8KB), prefetch depth 2, ONE barrier per tile,
// counted vmcnt(4).  Softmax internals = round-5-verified (exp2f + clamp,
// f32 VALU lsum) — controlled experiment isolating the schedule.
// Grid (16 combo, 16 nblk, 4 ksplit): same-combo blocks share one XCD.
// ---------------------------------------------------------------------------
__global__ __launch_bounds__(256, 4) void attn_mfma(const __hip_bfloat16* __restrict__ Qg,
                                                    const __hip_bfloat16* __restrict__ Kg,
                                                    const __hip_bfloat16* __restrict__ Vtg,
                                                    __hip_bfloat16* __restrict__ OTb,
                                                    float* __restrict__ Lp) {
    const int combo = blockIdx.x;          // bf*4 + h
    const int bf = combo >> 2, h = combo & 3;
    const int n0 = blockIdx.y * 128;
    const int split = blockIdx.z;
    const int kbase = split * (NPTS / 4);
    const int NT = NPTS / 4 / 32;          // 16 k-tiles of 32 per split

    __shared__ __align__(16) char smem[32768];   // 4 bufs x (K 4KB | V 4KB)

    const int t = threadIdx.x;
    const int lane = t & 63, w = t >> 6;
    const int l15 = lane & 15, g = (lane >> 4) & 3;

    // staging lane mappings (pre-swizzled global source, linear LDS dest)
    const int krow = w * 8 + (lane >> 3), kslot = lane & 7;   // 8 K rows / wave
    const int vrow = w * 16 + (lane >> 2), vslot = lane & 3;  // 16 V rows / wave
    const int kcs = (kslot ^ (krow & 7)) * 8;
    const int vcs = (vslot ^ ((vrow >> 1) & 3)) * 8;

    // Q B-fragments: frag f covers q rows n0 + w*32 + f*16 + l15
    const __hip_bfloat16* qbase =
        Qg + ((size_t)bf * NPTS + n0 + w * 32 + l15) * 256 + h * 64 + g * 8;
    bf16x8 qf[2][2];
    qf[0][0] = *(const bf16x8*)(qbase);
    qf[0][1] = *(const bf16x8*)(qbase + 32);
    qf[1][0] = *(const bf16x8*)(qbase + 16 * 256);
    qf[1][1] = *(const bf16x8*)(qbase + 16 * 256 + 32);

    const __hip_bfloat16* kgb = Kg + (size_t)bf * NPTS * 256 + h * 64;
    const __hip_bfloat16* vgb = Vtg + ((size_t)bf * 256 + h * 64) * NPTS;

    // hoisted LDS byte offsets
    int koff[2][2], voff[4];
#pragma unroll
    for (int tt = 0; tt < 2; ++tt) {
        const int row = tt * 16 + l15;
#pragma unroll
        for (int s = 0; s < 2; ++s)
            koff[tt][s] = row * 128 + (((s * 4 + g) ^ (row & 7)) << 4);
    }
#pragma unroll
    for (int ct = 0; ct < 4; ++ct) {
        const int row = ct * 16 + l15;
        voff[ct] = 4096 + row * 64 + ((g ^ ((row >> 1) & 3)) << 4);
    }

    f32x4 oacc[2][4];
    float lsum[2] = {0.f, 0.f};
#pragma unroll
    for (int f = 0; f < 2; ++f)
#pragma unroll
        for (int r = 0; r < 4; ++r) oacc[f][r] = (f32x4){0.f, 0.f, 0.f, 0.f};

    auto stage = [&](int kt) {
        const int bsel = kt & 3;
        const __hip_bfloat16* ksrc = kgb + (size_t)(kbase + kt * 32 + krow) * 256 + kcs;
        __builtin_amdgcn_global_load_lds((const glob_char*)ksrc,
            (lds_char*)(smem + bsel * 8192 + w * 1024), 16, 0, 0);
        const __hip_bfloat16* vsrc = vgb + (size_t)vrow * NPTS + kbase + kt * 32 + vcs;
        __builtin_amdgcn_global_load_lds((const glob_char*)vsrc,
            (lds_char*)(smem + bsel * 8192 + 4096 + w * 1024), 16, 0, 0);
    };

    auto tile = [&](int kt) {
        const char* B = smem + (kt & 3) * 8192;
        bf16x8 kf[2][2];
#pragma unroll
        for (int tt = 0; tt < 2; ++tt)
#pragma unroll
            for (int s = 0; s < 2; ++s)
                kf[tt][s] = *(const bf16x8*)(B + koff[tt][s]);

        bf16x8 pb[2];
#pragma unroll
        for (int f = 0; f < 2; ++f) {
            f32x4 st0 = (f32x4){0.f, 0.f, 0.f, 0.f}, st1 = st0;
            st0 = __builtin_amdgcn_mfma_f32_16x16x32_bf16(kf[0][0], qf[f][0], st0, 0, 0, 0);
            st0 = __builtin_amdgcn_mfma_f32_16x16x32_bf16(kf[0][1], qf[f][1], st0, 0, 0, 0);
            st1 = __builtin_amdgcn_mfma_f32_16x16x32_bf16(kf[1][0], qf[f][0], st1, 0, 0, 0);
            st1 = __builtin_amdgcn_mfma_f32_16x16x32_bf16(kf[1][1], qf[f][1], st1, 0, 0, 0);
            // round-5-verified softmax internals: exp2f + clamp, f32 VALU lsum
            float p00 = exp2f(fminf(st0[0], 126.f));
            float p01 = exp2f(fminf(st0[1], 126.f));
            float p02 = exp2f(fminf(st0[2], 126.f));
            float p03 = exp2f(fminf(st0[3], 126.f));
            float p10 = exp2f(fminf(st1[0], 126.f));
            float p11 = exp2f(fminf(st1[1], 126.f));
            float p12 = exp2f(fminf(st1[2], 126.f));
            float p13 = exp2f(fminf(st1[3], 126.f));
            lsum[f] += ((p00 + p01) + (p02 + p03)) + ((p10 + p11) + (p12 + p13));
            unsigned x0 = cvt_pk_bf16(p00, p01);
            unsigned x1 = cvt_pk_bf16(p02, p03);
            unsigned y0 = cvt_pk_bf16(p10, p11);
            unsigned y1 = cvt_pk_bf16(p12, p13);
            asm("v_permlane32_swap_b32 %0, %1" : "+v"(x0), "+v"(y0));
            asm("v_permlane16_swap_b32 %0, %1" : "+v"(x0), "+v"(y0));
            asm("v_permlane32_swap_b32 %0, %1" : "+v"(x1), "+v"(y1));
            asm("v_permlane16_swap_b32 %0, %1" : "+v"(x1), "+v"(y1));
            PBU pu;
            pu.u = (uint32x4){x0, x1, y0, y1};
            pb[f] = pu.v;
        }

        // PV: V fragments read once, feed both q-frags
#pragma unroll
        for (int ct = 0; ct < 4; ++ct) {
            bf16x8 vf = *(const bf16x8*)(B + voff[ct]);
            oacc[0][ct] = __builtin_amdgcn_mfma_f32_16x16x32_bf16(vf, pb[0], oacc[0][ct], 0, 0, 0);
            oacc[1][ct] = __builtin_amdgcn_mfma_f32_16x16x32_bf16(vf, pb[1], oacc[1][ct], 0, 0, 0);
        }
    };

    stage(0);
    stage(1);
    for (int kt = 0; kt < NT - 2; ++kt) {
        stage(kt + 2);
        asm volatile("s_waitcnt vmcnt(4)" ::: "memory");
        asm volatile("s_waitcnt lgkmcnt(0)" ::: "memory");
        __builtin_amdgcn_s_barrier();
        asm volatile("" ::: "memory");
        tile(kt);
    }
    asm volatile("s_waitcnt vmcnt(2)" ::: "memory");
    asm volatile("s_waitcnt lgkmcnt(0)" ::: "memory");
    __builtin_amdgcn_s_barrier();
    asm volatile("" ::: "memory");
    tile(NT - 2);
    asm volatile("s_waitcnt vmcnt(0)" ::: "memory");
    asm volatile("s_waitcnt lgkmcnt(0)" ::: "memory");
    __builtin_amdgcn_s_barrier();
    asm volatile("" ::: "memory");
    tile(NT - 1);

    // l[q]: sum over the 4 lane groups holding distinct k for each q
    float l0 = lsum[0], l1 = lsum[1];
    l0 += __shfl_xor(l0, 16);
    l0 += __shfl_xor(l0, 32);
    l1 += __shfl_xor(l1, 16);
    l1 += __shfl_xor(l1, 32);
    const int qq = n0 + w * 32 + l15;
    if (g == 0) {
        Lp[(size_t)(split * 16 + combo) * NPTS + qq] = l0;
        Lp[(size_t)(split * 16 + combo) * NPTS + qq + 16] = l1;
    }

    __hip_bfloat16* __restrict__ Op = OTb + (size_t)(split * 16 + combo) * 64 * NPTS;
#pragma unroll
    for (int ct = 0; ct < 4; ++ct)
#pragma unroll
        for (int r = 0; r < 4; ++r) {
            Op[(size_t)(ct * 16 + g * 4 + r) * NPTS + qq] = __float2bfloat16(oacc[0][ct][r]);
            Op[(size_t)(ct * 16 + g * 4 + r) * NPTS + qq + 16] = __float2bfloat16(oacc[1][ct][r]);
        }
}

// ---------------------------------------------------------------------------
// K3: combine 4 attention partials + normalize, then
//     xa = (O_f0 + O_f1) @ proj_w.T + proj_b ; frames = xa @ map_w.T + map_b
// ---------------------------------------------------------------------------
__global__ __launch_bounds__(256) void proj_frames(const __hip_bfloat16* __restrict__ OTb,
                                                   const float* __restrict__ Lp,
                                                   const float* __restrict__ proj_w,
                                                   const float* __restrict__ proj_b,
                                                   const float* __restrict__ map_w,
                                                   const float* __restrict__ map_b,
                                                   float* __restrict__ out,
                                                   float* __restrict__ frames0) {
    const int bh = blockIdx.y, b = bh >> 2, h = bh & 3;
    const int n0 = blockIdx.x * 64;
    const int cf0 = (b * 2 + 0) * 4 + h;
    const int cf1 = (b * 2 + 1) * 4 + h;

    __shared__ float Xs[64][68];   // [c][n]
    __shared__ float Ws[64][68];   // [j][c]
    __shared__ float xaS[64][68];  // [n][j]

    const int t = threadIdx.x;
    const int tx = t & 15, ty = t >> 4;
    const int nc = n0 + tx * 4;

    float4 L0 = make_float4(0.f, 0.f, 0.f, 0.f), L1 = L0;
#pragma unroll
    for (int s = 0; s < 4; ++s) {
        float4 a = *(const float4*)&Lp[(size_t)(s * 16 + cf0) * NPTS + nc];
        L0.x += a.x; L0.y += a.y; L0.z += a.z; L0.w += a.w;
        float4 c = *(const float4*)&Lp[(size_t)(s * 16 + cf1) * NPTS + nc];
        L1.x += c.x; L1.y += c.y; L1.z += c.z; L1.w += c.w;
    }
    float4 inv0 = make_float4(1.f / L0.x, 1.f / L0.y, 1.f / L0.z, 1.f / L0.w);
    float4 inv1 = make_float4(1.f / L1.x, 1.f / L1.y, 1.f / L1.z, 1.f / L1.w);

    for (int r = 0; r < 4; ++r) {
        int row = ty + 16 * r, col = tx * 4;   // row = c, col = n_local
        float x0 = 0.f, x1 = 0.f, x2 = 0.f, x3 = 0.f;
        float y0 = 0.f, y1 = 0.f, y2 = 0.f, y3 = 0.f;
#pragma unroll
        for (int s = 0; s < 4; ++s) {
            ushort4 u0 = *(const ushort4*)&OTb[((size_t)(s * 16 + cf0) * 64 + row) * NPTS + n0 + col];
            ushort4 u1 = *(const ushort4*)&OTb[((size_t)(s * 16 + cf1) * 64 + row) * NPTS + n0 + col];
            x0 += b2f(u0.x); x1 += b2f(u0.y); x2 += b2f(u0.z); x3 += b2f(u0.w);
            y0 += b2f(u1.x); y1 += b2f(u1.y); y2 += b2f(u1.z); y3 += b2f(u1.w);
        }
        Xs[row][col + 0] = x0 * inv0.x + y0 * inv1.x;
        Xs[row][col + 1] = x1 * inv0.y + y1 * inv1.y;
        Xs[row][col + 2] = x2 * inv0.z + y2 * inv1.z;
        Xs[row][col + 3] = x3 * inv0.w + y3 * inv1.w;
        *(float4*)&Ws[row][col] = *(const float4*)&proj_w[(size_t)row * 64 + col];
    }
    __syncthreads();

    float acc[4][4];
#pragma unroll
    for (int jj = 0; jj < 4; ++jj) {
        float bv = proj_b[tx + 16 * jj];
#pragma unroll
        for (int i = 0; i < 4; ++i) acc[i][jj] = bv;
    }
    for (int c = 0; c < 64; ++c) {
        float a[4], w[4];
#pragma unroll
        for (int i = 0; i < 4; ++i) a[i] = Xs[c][ty + 16 * i];
#pragma unroll
        for (int jj = 0; jj < 4; ++jj) w[jj] = Ws[tx + 16 * jj][c];
#pragma unroll
        for (int i = 0; i < 4; ++i)
#pragma unroll
            for (int jj = 0; jj < 4; ++jj) acc[i][jj] += a[i] * w[jj];
    }

#pragma unroll
    for (int i = 0; i < 4; ++i)
#pragma unroll
        for (int jj = 0; jj < 4; ++jj)
            xaS[ty + 16 * i][tx + 16 * jj] = acc[i][jj];

    if (h >= 1) {
        float* __restrict__ xa_out = out + (size_t)(b * 3 + h - 1) * NPTS * 64;
#pragma unroll
        for (int i = 0; i < 4; ++i)
#pragma unroll
            for (int jj = 0; jj < 4; ++jj)
                xa_out[(size_t)(n0 + ty + 16 * i) * 64 + tx + 16 * jj] = acc[i][jj];
    }
    __syncthreads();

    if (t < 192) {
        int r = t / 3, j = t % 3;
        float s = map_b[j];
        for (int c = 0; c < 64; ++c) s += xaS[r][c] * map_w[j * 64 + c];
        int n = n0 + r;
        if (h == 0) frames0[((size_t)b * NPTS + n) * 3 + j] = s;
        else        out[786432 + ((size_t)(b * 3 + h - 1) * NPTS + n) * 3 + j] = s;
    }
}

// ---------------------------------------------------------------------------
// K4a: chamfer partial mins.  grid (NPTS/256, NJC, 4); z = dir*2 + b.
// ---------------------------------------------------------------------------
__global__ __launch_bounds__(256) void chamfer_partial(const float* __restrict__ pc1,
                                                       const float* __restrict__ frames0,
                                                       float* __restrict__ partial) {
    const int z = blockIdx.z;          // dir*2 + b
    const int dir = z >> 1, b = z & 1;
    const int i = blockIdx.x * 256 + threadIdx.x;
    const int j0 = blockIdx.y * JCH;
    const float* __restrict__ px = pc1 + (size_t)b * 3 * NPTS;
    const float* __restrict__ fr = frames0 + (size_t)b * NPTS * 3;

    __shared__ float4 sj[JCH];
    if (threadIdx.x < JCH) {
        int jj = j0 + threadIdx.x;
        float bx = px[jj], by = px[NPTS + jj], bz = px[2 * NPTS + jj];
        if (dir == 1) { bx += fr[jj * 3]; by += fr[jj * 3 + 1]; bz += fr[jj * 3 + 2]; }
        sj[threadIdx.x] = make_float4(bx, by, bz, bx * bx + by * by + bz * bz);
    }
    float ax = px[i], ay = px[NPTS + i], az = px[2 * NPTS + i];
    if (dir == 0) { ax += fr[i * 3]; ay += fr[i * 3 + 1]; az += fr[i * 3 + 2]; }
    const float a2 = ax * ax + ay * ay + az * az;
    __syncthreads();

    float best = 1e30f;
#pragma unroll 4
    for (int k = 0; k < JCH; ++k) {
        float4 p = sj[k];
        float d = a2 + p.w - 2.0f * (ax * p.x + ay * p.y + az * p.z);
        best = fminf(best, d);
    }
    partial[((size_t)z * NJC + blockIdx.y) * NPTS + i] = best;
}

// ---------------------------------------------------------------------------
// K4b: min over chunks + per-block sum. 32 blocks x 256 thr.
// ---------------------------------------------------------------------------
__global__ __launch_bounds__(256) void chamfer_minsum(const float* __restrict__ partial,
                                                      double* __restrict__ sums) {
    const int gid = blockIdx.x * 256 + threadIdx.x;
    const int z = gid >> 11, i = gid & 2047;
    float best = 1e30f;
#pragma unroll
    for (int c = 0; c < NJC; ++c)
        best = fminf(best, partial[((size_t)z * NJC + c) * NPTS + i]);
    __shared__ double sm[256];
    sm[threadIdx.x] = (double)best;
    __syncthreads();
    for (int off = 128; off > 0; off >>= 1) {
        if (threadIdx.x < off) sm[threadIdx.x] += sm[threadIdx.x + off];
        __syncthreads();
    }
    if (threadIdx.x == 0) sums[blockIdx.x] = sm[0];
}

__global__ void chamfer_final(const double* __restrict__ sums, float* __restrict__ loss_out) {
    if (threadIdx.x == 0) {
        double s = 0.0;
        for (int k = 0; k < 32; ++k) s += sums[k];
        loss_out[0] = (float)(s / 4096.0);
    }
}

// ---------------------------------------------------------------------------
extern "C" void kernel_launch(void* const* d_in, const int* in_sizes, int n_in,
                              void* d_out, int out_size, void* d_ws, size_t ws_size,
                              hipStream_t stream) {
    const float* xs     = (const float*)d_in[0];
    const float* pc1    = (const float*)d_in[1];
    // d_in[2] = pc2 (unused by reference)
    const float* gamma  = (const float*)d_in[3];
    const float* beta   = (const float*)d_in[4];
    const float* q_w    = (const float*)d_in[5];
    const float* kv_w   = (const float*)d_in[6];
    const float* proj_w = (const float*)d_in[7];
    const float* proj_b = (const float*)d_in[8];
    const float* map_w  = (const float*)d_in[9];
    const float* map_b  = (const float*)d_in[10];
    float* out = (float*)d_out;

    char* ws = (char*)d_ws;
    __hip_bfloat16* Qg  = (__hip_bfloat16*)(ws);              // 4 MiB
    __hip_bfloat16* Kg  = (__hip_bfloat16*)(ws + 4194304);    // 4 MiB
    __hip_bfloat16* Vtg = (__hip_bfloat16*)(ws + 8388608);    // 4 MiB
    __hip_bfloat16* OTb = (__hip_bfloat16*)(ws + 12582912);   // 4*16*64*2048*2 = 16 MiB
    float* Wp      = (float*)(ws + 29360128);                 // 768*64*4
    float* bp      = (float*)(ws + 29556736);                 // 768*4
    float* frames0 = (float*)(ws + 29559808);                 // 2*2048*3*4
    float* partial = (float*)(ws + 29609984);                 // 512 KiB
    double* sums   = (double*)(ws + 30134272);                // 32*8
    float* Lp      = (float*)(ws + 30134528);                 // 4*16*2048*4 = 512 KiB

    hipLaunchKernelGGL(prep_weights, dim3(3), dim3(256), 0, stream,
                       gamma, beta, q_w, kv_w, Wp, bp);
    hipLaunchKernelGGL(qkv_gemm, dim3(32, 12, 4), dim3(256), 0, stream,
                       xs, Wp, bp, Qg, Kg, Vtg);
    hipLaunchKernelGGL(attn_mfma, dim3(16, 16, 4), dim3(256), 0, stream,
                       Qg, Kg, Vtg, OTb, Lp);
    hipLaunchKernelGGL(proj_frames, dim3(32, 8), dim3(256), 0, stream,
                       OTb, Lp, proj_w, proj_b, map_w, map_b, out, frames0);
    hipLaunchKernelGGL(chamfer_partial, dim3(NPTS / 256, NJC, 4), dim3(256), 0, stream,
                       pc1, frames0, partial);
    hipLaunchKernelGGL(chamfer_minsum, dim3(32), dim3(256), 0, stream,
                       partial, sums);
    hipLaunchKernelGGL(chamfer_final, dim3(1), dim3(64), 0, stream,
                       sums, out + 823296);
}

// Round 8
// 85.593 us; speedup vs baseline: 10.2246x; 1.0427x over previous
//
#include <hip/hip_runtime.h>
#include <hip/hip_bf16.h>

#define NPTS 2048
#define LOG2E 1.4426950408889634f
#define NJC 16     // chamfer j-chunks
#define JCH 128    // points per chunk
#define KSPLIT 8

typedef short bf16x8 __attribute__((ext_vector_type(8)));
typedef float f32x4 __attribute__((ext_vector_type(4)));
typedef unsigned uint32x4 __attribute__((ext_vector_type(4)));
typedef __attribute__((address_space(3))) char lds_char;
typedef __attribute__((address_space(1))) const char glob_char;

union PBU { uint32x4 u; bf16x8 v; };

static __device__ __forceinline__ unsigned cvt_pk_bf16(float a, float b) {
    unsigned r;
    asm("v_cvt_pk_bf16_f32 %0, %1, %2" : "=v"(r) : "v"(a), "v"(b));
    return r;
}
static __device__ __forceinline__ float b2f(unsigned short u) {
    return __uint_as_float((unsigned)u << 16);
}

// ---------------------------------------------------------------------------
// K0: fold BN affine + softmax scale + log2e into combined QKV weights.
// ---------------------------------------------------------------------------
__global__ void prep_weights(const float* __restrict__ gamma, const float* __restrict__ beta,
                             const float* __restrict__ q_w, const float* __restrict__ kv_w,
                             float* __restrict__ Wp, float* __restrict__ bp) {
    int j = blockIdx.x * blockDim.x + threadIdx.x;
    if (j >= 768) return;
    const float inv = 1.0f / sqrtf(1.0f + 1e-5f);
    const float* src;
    float scale;
    if (j < 256) { src = q_w + j * 64;          scale = 0.125f * LOG2E; }
    else         { src = kv_w + (j - 256) * 64; scale = 1.0f; }
    float b = 0.f;
    for (int c = 0; c < 64; ++c) {
        float w = src[c];
        Wp[j * 64 + c] = w * gamma[c] * inv * scale;
        b += w * beta[c];
    }
    bp[j] = b * scale;
}

// ---------------------------------------------------------------------------
// K1: QKV GEMM.  Emits bf16 Qg/Kg [bf][n][256] and transposed bf16 Vt [bf][256][n].
// ---------------------------------------------------------------------------
__global__ __launch_bounds__(256) void qkv_gemm(const float* __restrict__ xs,
                                                const float* __restrict__ Wp,
                                                const float* __restrict__ bp,
                                                __hip_bfloat16* __restrict__ Qg,
                                                __hip_bfloat16* __restrict__ Kg,
                                                __hip_bfloat16* __restrict__ Vtg) {
    const int bf = blockIdx.z;            // b*2 + f01
    const int b = bf >> 1, f01 = bf & 1;
    const int jt = blockIdx.y;            // 0..11  (j block of 64)
    const int f_src = (jt < 4) ? f01 : (3 - f01);
    const int n0 = blockIdx.x * 64;
    const float* __restrict__ A = xs + (size_t)((b * 4 + f_src) * 64) * NPTS; // [c][n]

    __shared__ float As[64][68];   // [c][n] staged; reused as transpose bounce
    __shared__ float Ws[64][68];   // [j][c], padded stride

    const int t = threadIdx.x;
    const int tx = t & 15, ty = t >> 4;

    for (int r = 0; r < 4; ++r) {
        int row = ty + 16 * r;
        int col = tx * 4;
        *(float4*)&As[row][col] = *(const float4*)&A[(size_t)row * NPTS + n0 + col];
        *(float4*)&Ws[row][col] = *(const float4*)&Wp[(size_t)(jt * 64 + row) * 64 + col];
    }
    __syncthreads();

    float acc[4][4];
#pragma unroll
    for (int jj = 0; jj < 4; ++jj) {
        float bv = bp[jt * 64 + tx + 16 * jj];
#pragma unroll
        for (int i = 0; i < 4; ++i) acc[i][jj] = bv;
    }
    for (int c = 0; c < 64; ++c) {
        float a[4], w[4];
#pragma unroll
        for (int i = 0; i < 4; ++i) a[i] = As[c][ty + 16 * i];
#pragma unroll
        for (int jj = 0; jj < 4; ++jj) w[jj] = Ws[tx + 16 * jj][c];
#pragma unroll
        for (int i = 0; i < 4; ++i)
#pragma unroll
            for (int jj = 0; jj < 4; ++jj) acc[i][jj] += a[i] * w[jj];
    }

    if (jt < 8) {
        __hip_bfloat16* __restrict__ dst = (jt < 4 ? Qg : Kg) + (size_t)bf * NPTS * 256;
        const int jb = (jt & 3) * 64;
#pragma unroll
        for (int i = 0; i < 4; ++i) {
            int n = n0 + ty + 16 * i;
#pragma unroll
            for (int jj = 0; jj < 4; ++jj)
                dst[(size_t)n * 256 + jb + tx + 16 * jj] = __float2bfloat16(acc[i][jj]);
        }
    } else {
        // V: transpose through LDS, write Vt[c][n] bf16 coalesced
        __syncthreads();
#pragma unroll
        for (int i = 0; i < 4; ++i)
#pragma unroll
            for (int jj = 0; jj < 4; ++jj)
                As[tx + 16 * jj][ty + 16 * i] = acc[i][jj];   // [j_local][n_local]
        __syncthreads();
        const int row = t >> 2, c0 = (t & 3) * 16;
        __hip_bfloat16* __restrict__ dst =
            Vtg + ((size_t)bf * 256 + (jt - 8) * 64 + row) * NPTS + n0 + c0;
#pragma unroll
        for (int c = 0; c < 16; ++c) dst[c] = __float2bfloat16(As[row][c0 + c]);
    }
}

// ---------------------------------------------------------------------------
// K2: MFMA flash attention, swapped-operand, 32 q/wave, 32-k tiles,
// QUAD-buffered LDS (4 x 8KB), prefetch depth 2, ONE barrier per tile,
// counted vmcnt(4).  KSPLIT=8 for residency (8 blocks/CU of work, 5 resident).
// Grid (16 combo, 16 nblk, 8 ksplit): same-combo blocks share one XCD.
// ---------------------------------------------------------------------------
__global__ __launch_bounds__(256, 4) void attn_mfma(const __hip_bfloat16* __restrict__ Qg,
                                                    const __hip_bfloat16* __restrict__ Kg,
                                                    const __hip_bfloat16* __restrict__ Vtg,
                                                    __hip_bfloat16* __restrict__ OTb,
                                                    float* __restrict__ Lp) {
    const int combo = blockIdx.x;          // bf*4 + h
    const int bf = combo >> 2, h = combo & 3;
    const int n0 = blockIdx.y * 128;
    const int split = blockIdx.z;
    const int kbase = split * (NPTS / KSPLIT);
    const int NT = NPTS / KSPLIT / 32;     // 8 k-tiles of 32 per split

    __shared__ __align__(16) char smem[32768];   // 4 bufs x (K 4KB | V 4KB)

    const int t = threadIdx.x;
    const int lane = t & 63, w = t >> 6;
    const int l15 = lane & 15, g = (lane >> 4) & 3;

    // staging lane mappings (pre-swizzled global source, linear LDS dest)
    const int krow = w * 8 + (lane >> 3), kslot = lane & 7;   // 8 K rows / wave
    const int vrow = w * 16 + (lane >> 2), vslot = lane & 3;  // 16 V rows / wave
    const int kcs = (kslot ^ (krow & 7)) * 8;
    const int vcs = (vslot ^ ((vrow >> 1) & 3)) * 8;

    // Q B-fragments: frag f covers q rows n0 + w*32 + f*16 + l15
    const __hip_bfloat16* qbase =
        Qg + ((size_t)bf * NPTS + n0 + w * 32 + l15) * 256 + h * 64 + g * 8;
    bf16x8 qf[2][2];
    qf[0][0] = *(const bf16x8*)(qbase);
    qf[0][1] = *(const bf16x8*)(qbase + 32);
    qf[1][0] = *(const bf16x8*)(qbase + 16 * 256);
    qf[1][1] = *(const bf16x8*)(qbase + 16 * 256 + 32);

    const __hip_bfloat16* kgb = Kg + (size_t)bf * NPTS * 256 + h * 64;
    const __hip_bfloat16* vgb = Vtg + ((size_t)bf * 256 + h * 64) * NPTS;

    // hoisted LDS byte offsets
    int koff[2][2], voff[4];
#pragma unroll
    for (int tt = 0; tt < 2; ++tt) {
        const int row = tt * 16 + l15;
#pragma unroll
        for (int s = 0; s < 2; ++s)
            koff[tt][s] = row * 128 + (((s * 4 + g) ^ (row & 7)) << 4);
    }
#pragma unroll
    for (int ct = 0; ct < 4; ++ct) {
        const int row = ct * 16 + l15;
        voff[ct] = 4096 + row * 64 + ((g ^ ((row >> 1) & 3)) << 4);
    }

    f32x4 oacc[2][4];
    float lsum[2] = {0.f, 0.f};
#pragma unroll
    for (int f = 0; f < 2; ++f)
#pragma unroll
        for (int r = 0; r < 4; ++r) oacc[f][r] = (f32x4){0.f, 0.f, 0.f, 0.f};

    auto stage = [&](int kt) {
        const int bsel = kt & 3;
        const __hip_bfloat16* ksrc = kgb + (size_t)(kbase + kt * 32 + krow) * 256 + kcs;
        __builtin_amdgcn_global_load_lds((const glob_char*)ksrc,
            (lds_char*)(smem + bsel * 8192 + w * 1024), 16, 0, 0);
        const __hip_bfloat16* vsrc = vgb + (size_t)vrow * NPTS + kbase + kt * 32 + vcs;
        __builtin_amdgcn_global_load_lds((const glob_char*)vsrc,
            (lds_char*)(smem + bsel * 8192 + 4096 + w * 1024), 16, 0, 0);
    };

    auto tile = [&](int kt) {
        const char* B = smem + (kt & 3) * 8192;
        bf16x8 kf[2][2];
#pragma unroll
        for (int tt = 0; tt < 2; ++tt)
#pragma unroll
            for (int s = 0; s < 2; ++s)
                kf[tt][s] = *(const bf16x8*)(B + koff[tt][s]);

        bf16x8 pb[2];
#pragma unroll
        for (int f = 0; f < 2; ++f) {
            f32x4 st0 = (f32x4){0.f, 0.f, 0.f, 0.f}, st1 = st0;
            st0 = __builtin_amdgcn_mfma_f32_16x16x32_bf16(kf[0][0], qf[f][0], st0, 0, 0, 0);
            st0 = __builtin_amdgcn_mfma_f32_16x16x32_bf16(kf[0][1], qf[f][1], st0, 0, 0, 0);
            st1 = __builtin_amdgcn_mfma_f32_16x16x32_bf16(kf[1][0], qf[f][0], st1, 0, 0, 0);
            st1 = __builtin_amdgcn_mfma_f32_16x16x32_bf16(kf[1][1], qf[f][1], st1, 0, 0, 0);
            // verified softmax internals (no clamp: |S| <~ 0.03 by construction)
            float p00 = exp2f(st0[0]);
            float p01 = exp2f(st0[1]);
            float p02 = exp2f(st0[2]);
            float p03 = exp2f(st0[3]);
            float p10 = exp2f(st1[0]);
            float p11 = exp2f(st1[1]);
            float p12 = exp2f(st1[2]);
            float p13 = exp2f(st1[3]);
            lsum[f] += ((p00 + p01) + (p02 + p03)) + ((p10 + p11) + (p12 + p13));
            unsigned x0 = cvt_pk_bf16(p00, p01);
            unsigned x1 = cvt_pk_bf16(p02, p03);
            unsigned y0 = cvt_pk_bf16(p10, p11);
            unsigned y1 = cvt_pk_bf16(p12, p13);
            asm("v_permlane32_swap_b32 %0, %1" : "+v"(x0), "+v"(y0));
            asm("v_permlane16_swap_b32 %0, %1" : "+v"(x0), "+v"(y0));
            asm("v_permlane32_swap_b32 %0, %1" : "+v"(x1), "+v"(y1));
            asm("v_permlane16_swap_b32 %0, %1" : "+v"(x1), "+v"(y1));
            PBU pu;
            pu.u = (uint32x4){x0, x1, y0, y1};
            pb[f] = pu.v;
        }

        // PV: V fragments read once, feed both q-frags
#pragma unroll
        for (int ct = 0; ct < 4; ++ct) {
            bf16x8 vf = *(const bf16x8*)(B + voff[ct]);
            oacc[0][ct] = __builtin_amdgcn_mfma_f32_16x16x32_bf16(vf, pb[0], oacc[0][ct], 0, 0, 0);
            oacc[1][ct] = __builtin_amdgcn_mfma_f32_16x16x32_bf16(vf, pb[1], oacc[1][ct], 0, 0, 0);
        }
    };

    stage(0);
    stage(1);
    for (int kt = 0; kt < NT - 2; ++kt) {
        stage(kt + 2);
        asm volatile("s_waitcnt vmcnt(4)" ::: "memory");
        asm volatile("s_waitcnt lgkmcnt(0)" ::: "memory");
        __builtin_amdgcn_s_barrier();
        asm volatile("" ::: "memory");
        tile(kt);
    }
    asm volatile("s_waitcnt vmcnt(2)" ::: "memory");
    asm volatile("s_waitcnt lgkmcnt(0)" ::: "memory");
    __builtin_amdgcn_s_barrier();
    asm volatile("" ::: "memory");
    tile(NT - 2);
    asm volatile("s_waitcnt vmcnt(0)" ::: "memory");
    asm volatile("s_waitcnt lgkmcnt(0)" ::: "memory");
    __builtin_amdgcn_s_barrier();
    asm volatile("" ::: "memory");
    tile(NT - 1);

    // l[q]: sum over the 4 lane groups holding distinct k for each q
    float l0 = lsum[0], l1 = lsum[1];
    l0 += __shfl_xor(l0, 16);
    l0 += __shfl_xor(l0, 32);
    l1 += __shfl_xor(l1, 16);
    l1 += __shfl_xor(l1, 32);
    const int qq = n0 + w * 32 + l15;
    if (g == 0 && lane < 16) {
        Lp[(size_t)(split * 16 + combo) * NPTS + qq] = l0;
        Lp[(size_t)(split * 16 + combo) * NPTS + qq + 16] = l1;
    }

    __hip_bfloat16* __restrict__ Op = OTb + (size_t)(split * 16 + combo) * 64 * NPTS;
#pragma unroll
    for (int ct = 0; ct < 4; ++ct)
#pragma unroll
        for (int r = 0; r < 4; ++r) {
            Op[(size_t)(ct * 16 + g * 4 + r) * NPTS + qq] = __float2bfloat16(oacc[0][ct][r]);
            Op[(size_t)(ct * 16 + g * 4 + r) * NPTS + qq + 16] = __float2bfloat16(oacc[1][ct][r]);
        }
}

// ---------------------------------------------------------------------------
// K3: combine KSPLIT attention partials + normalize, then
//     xa = (O_f0 + O_f1) @ proj_w.T + proj_b ; frames = xa @ map_w.T + map_b
// ---------------------------------------------------------------------------
__global__ __launch_bounds__(256) void proj_frames(const __hip_bfloat16* __restrict__ OTb,
                                                   const float* __restrict__ Lp,
                                                   const float* __restrict__ proj_w,
                                                   const float* __restrict__ proj_b,
                                                   const float* __restrict__ map_w,
                                                   const float* __restrict__ map_b,
                                                   float* __restrict__ out,
                                                   float* __restrict__ frames0) {
    const int bh = blockIdx.y, b = bh >> 2, h = bh & 3;
    const int n0 = blockIdx.x * 64;
    const int cf0 = (b * 2 + 0) * 4 + h;
    const int cf1 = (b * 2 + 1) * 4 + h;

    __shared__ float Xs[64][68];   // [c][n]
    __shared__ float Ws[64][68];   // [j][c]
    __shared__ float xaS[64][68];  // [n][j]

    const int t = threadIdx.x;
    const int tx = t & 15, ty = t >> 4;
    const int nc = n0 + tx * 4;

    float4 L0 = make_float4(0.f, 0.f, 0.f, 0.f), L1 = L0;
#pragma unroll
    for (int s = 0; s < KSPLIT; ++s) {
        float4 a = *(const float4*)&Lp[(size_t)(s * 16 + cf0) * NPTS + nc];
        L0.x += a.x; L0.y += a.y; L0.z += a.z; L0.w += a.w;
        float4 c = *(const float4*)&Lp[(size_t)(s * 16 + cf1) * NPTS + nc];
        L1.x += c.x; L1.y += c.y; L1.z += c.z; L1.w += c.w;
    }
    float4 inv0 = make_float4(1.f / L0.x, 1.f / L0.y, 1.f / L0.z, 1.f / L0.w);
    float4 inv1 = make_float4(1.f / L1.x, 1.f / L1.y, 1.f / L1.z, 1.f / L1.w);

    for (int r = 0; r < 4; ++r) {
        int row = ty + 16 * r, col = tx * 4;   // row = c, col = n_local
        float x0 = 0.f, x1 = 0.f, x2 = 0.f, x3 = 0.f;
        float y0 = 0.f, y1 = 0.f, y2 = 0.f, y3 = 0.f;
#pragma unroll
        for (int s = 0; s < KSPLIT; ++s) {
            ushort4 u0 = *(const ushort4*)&OTb[((size_t)(s * 16 + cf0) * 64 + row) * NPTS + n0 + col];
            ushort4 u1 = *(const ushort4*)&OTb[((size_t)(s * 16 + cf1) * 64 + row) * NPTS + n0 + col];
            x0 += b2f(u0.x); x1 += b2f(u0.y); x2 += b2f(u0.z); x3 += b2f(u0.w);
            y0 += b2f(u1.x); y1 += b2f(u1.y); y2 += b2f(u1.z); y3 += b2f(u1.w);
        }
        Xs[row][col + 0] = x0 * inv0.x + y0 * inv1.x;
        Xs[row][col + 1] = x1 * inv0.y + y1 * inv1.y;
        Xs[row][col + 2] = x2 * inv0.z + y2 * inv1.z;
        Xs[row][col + 3] = x3 * inv0.w + y3 * inv1.w;
        *(float4*)&Ws[row][col] = *(const float4*)&proj_w[(size_t)row * 64 + col];
    }
    __syncthreads();

    float acc[4][4];
#pragma unroll
    for (int jj = 0; jj < 4; ++jj) {
        float bv = proj_b[tx + 16 * jj];
#pragma unroll
        for (int i = 0; i < 4; ++i) acc[i][jj] = bv;
    }
    for (int c = 0; c < 64; ++c) {
        float a[4], w[4];
#pragma unroll
        for (int i = 0; i < 4; ++i) a[i] = Xs[c][ty + 16 * i];
#pragma unroll
        for (int jj = 0; jj < 4; ++jj) w[jj] = Ws[tx + 16 * jj][c];
#pragma unroll
        for (int i = 0; i < 4; ++i)
#pragma unroll
            for (int jj = 0; jj < 4; ++jj) acc[i][jj] += a[i] * w[jj];
    }

#pragma unroll
    for (int i = 0; i < 4; ++i)
#pragma unroll
        for (int jj = 0; jj < 4; ++jj)
            xaS[ty + 16 * i][tx + 16 * jj] = acc[i][jj];

    if (h >= 1) {
        float* __restrict__ xa_out = out + (size_t)(b * 3 + h - 1) * NPTS * 64;
#pragma unroll
        for (int i = 0; i < 4; ++i)
#pragma unroll
            for (int jj = 0; jj < 4; ++jj)
                xa_out[(size_t)(n0 + ty + 16 * i) * 64 + tx + 16 * jj] = acc[i][jj];
    }
    __syncthreads();

    if (t < 192) {
        int r = t / 3, j = t % 3;
        float s = map_b[j];
        for (int c = 0; c < 64; ++c) s += xaS[r][c] * map_w[j * 64 + c];
        int n = n0 + r;
        if (h == 0) frames0[((size_t)b * NPTS + n) * 3 + j] = s;
        else        out[786432 + ((size_t)(b * 3 + h - 1) * NPTS + n) * 3 + j] = s;
    }
}

// ---------------------------------------------------------------------------
// K4a: chamfer partial mins.  grid (NPTS/256, NJC, 4); z = dir*2 + b.
// ---------------------------------------------------------------------------
__global__ __launch_bounds__(256) void chamfer_partial(const float* __restrict__ pc1,
                                                       const float* __restrict__ frames0,
                                                       float* __restrict__ partial) {
    const int z = blockIdx.z;          // dir*2 + b
    const int dir = z >> 1, b = z & 1;
    const int i = blockIdx.x * 256 + threadIdx.x;
    const int j0 = blockIdx.y * JCH;
    const float* __restrict__ px = pc1 + (size_t)b * 3 * NPTS;
    const float* __restrict__ fr = frames0 + (size_t)b * NPTS * 3;

    __shared__ float4 sj[JCH];
    if (threadIdx.x < JCH) {
        int jj = j0 + threadIdx.x;
        float bx = px[jj], by = px[NPTS + jj], bz = px[2 * NPTS + jj];
        if (dir == 1) { bx += fr[jj * 3]; by += fr[jj * 3 + 1]; bz += fr[jj * 3 + 2]; }
        sj[threadIdx.x] = make_float4(bx, by, bz, bx * bx + by * by + bz * bz);
    }
    float ax = px[i], ay = px[NPTS + i], az = px[2 * NPTS + i];
    if (dir == 0) { ax += fr[i * 3]; ay += fr[i * 3 + 1]; az += fr[i * 3 + 2]; }
    const float a2 = ax * ax + ay * ay + az * az;
    __syncthreads();

    float best = 1e30f;
#pragma unroll 4
    for (int k = 0; k < JCH; ++k) {
        float4 p = sj[k];
        float d = a2 + p.w - 2.0f * (ax * p.x + ay * p.y + az * p.z);
        best = fminf(best, d);
    }
    partial[((size_t)z * NJC + blockIdx.y) * NPTS + i] = best;
}

// ---------------------------------------------------------------------------
// K4b: min over chunks + per-block sum. 32 blocks x 256 thr.
// ---------------------------------------------------------------------------
__global__ __launch_bounds__(256) void chamfer_minsum(const float* __restrict__ partial,
                                                      double* __restrict__ sums) {
    const int gid = blockIdx.x * 256 + threadIdx.x;
    const int z = gid >> 11, i = gid & 2047;
    float best = 1e30f;
#pragma unroll
    for (int c = 0; c < NJC; ++c)
        best = fminf(best, partial[((size_t)z * NJC + c) * NPTS + i]);
    __shared__ double sm[256];
    sm[threadIdx.x] = (double)best;
    __syncthreads();
    for (int off = 128; off > 0; off >>= 1) {
        if (threadIdx.x < off) sm[threadIdx.x] += sm[threadIdx.x + off];
        __syncthreads();
    }
    if (threadIdx.x == 0) sums[blockIdx.x] = sm[0];
}

__global__ void chamfer_final(const double* __restrict__ sums, float* __restrict__ loss_out) {
    if (threadIdx.x == 0) {
        double s = 0.0;
        for (int k = 0; k < 32; ++k) s += sums[k];
        loss_out[0] = (float)(s / 4096.0);
    }
}

// ---------------------------------------------------------------------------
extern "C" void kernel_launch(void* const* d_in, const int* in_sizes, int n_in,
                              void* d_out, int out_size, void* d_ws, size_t ws_size,
                              hipStream_t stream) {
    const float* xs     = (const float*)d_in[0];
    const float* pc1    = (const float*)d_in[1];
    // d_in[2] = pc2 (unused by reference)
    const float* gamma  = (const float*)d_in[3];
    const float* beta   = (const float*)d_in[4];
    const float* q_w    = (const float*)d_in[5];
    const float* kv_w   = (const float*)d_in[6];
    const float* proj_w = (const float*)d_in[7];
    const float* proj_b = (const float*)d_in[8];
    const float* map_w  = (const float*)d_in[9];
    const float* map_b  = (const float*)d_in[10];
    float* out = (float*)d_out;

    char* ws = (char*)d_ws;
    __hip_bfloat16* Qg  = (__hip_bfloat16*)(ws);              // 4 MiB
    __hip_bfloat16* Kg  = (__hip_bfloat16*)(ws + 4194304);    // 4 MiB
    __hip_bfloat16* Vtg = (__hip_bfloat16*)(ws + 8388608);    // 4 MiB
    __hip_bfloat16* OTb = (__hip_bfloat16*)(ws + 12582912);   // 8*16*64*2048*2 = 32 MiB
    float* Wp      = (float*)(ws + 46137344);                 // 768*64*4
    float* bp      = (float*)(ws + 46333952);                 // 768*4
    float* frames0 = (float*)(ws + 46337024);                 // 2*2048*3*4
    float* partial = (float*)(ws + 46386176);                 // 512 KiB
    double* sums   = (double*)(ws + 46910464);                // 32*8
    float* Lp      = (float*)(ws + 46910720);                 // 8*16*2048*4 = 1 MiB

    hipLaunchKernelGGL(prep_weights, dim3(3), dim3(256), 0, stream,
                       gamma, beta, q_w, kv_w, Wp, bp);
    hipLaunchKernelGGL(qkv_gemm, dim3(32, 12, 4), dim3(256), 0, stream,
                       xs, Wp, bp, Qg, Kg, Vtg);
    hipLaunchKernelGGL(attn_mfma, dim3(16, 16, KSPLIT), dim3(256), 0, stream,
                       Qg, Kg, Vtg, OTb, Lp);
    hipLaunchKernelGGL(proj_frames, dim3(32, 8), dim3(256), 0, stream,
                       OTb, Lp, proj_w, proj_b, map_w, map_b, out, frames0);
    hipLaunchKernelGGL(chamfer_partial, dim3(NPTS / 256, NJC, 4), dim3(256), 0, stream,
                       pc1, frames0, partial);
    hipLaunchKernelGGL(chamfer_minsum, dim3(32), dim3(256), 0, stream,
                       partial, sums);
    hipLaunchKernelGGL(chamfer_final, dim3(1), dim3(64), 0, stream,
                       sums, out + 823296);
}

// Round 9
// 80.433 us; speedup vs baseline: 10.8805x; 1.0642x over previous
//
#include <hip/hip_runtime.h>
#include <hip/hip_bf16.h>

#define NPTS 2048
#define LOG2E 1.4426950408889634f
#define NJC 16     // chamfer j-chunks
#define JCH 128    // points per chunk
#define KSPLIT 8

typedef short bf16x8 __attribute__((ext_vector_type(8)));
typedef float f32x4 __attribute__((ext_vector_type(4)));
typedef unsigned uint32x4 __attribute__((ext_vector_type(4)));
typedef __attribute__((address_space(3))) char lds_char;
typedef __attribute__((address_space(1))) const char glob_char;

union PBU { uint32x4 u; bf16x8 v; };

static __device__ __forceinline__ unsigned cvt_pk_bf16(float a, float b) {
    unsigned r;
    asm("v_cvt_pk_bf16_f32 %0, %1, %2" : "=v"(r) : "v"(a), "v"(b));
    return r;
}
static __device__ __forceinline__ float b2f(unsigned short u) {
    return __uint_as_float((unsigned)u << 16);
}

// ---------------------------------------------------------------------------
// K0: cast weights to bf16.  Wpb[768][64]: rows 0..255 = q_w x (0.125*log2e),
// 256..511 = kv_w rows 0..255 (K), 512..767 = kv_w rows 256..511 (V).
// BN affine is folded into xT (xt_kernel), so no gamma/beta here, no bias.
// ---------------------------------------------------------------------------
__global__ void prep_weights(const float* __restrict__ q_w, const float* __restrict__ kv_w,
                             __hip_bfloat16* __restrict__ Wpb) {
    int j = blockIdx.x * blockDim.x + threadIdx.x;
    if (j >= 768) return;
    const float* src;
    float scale;
    if (j < 256) { src = q_w + j * 64;          scale = 0.125f * LOG2E; }
    else         { src = kv_w + (j - 256) * 64; scale = 1.0f; }
    for (int c = 0; c < 64; ++c)
        Wpb[j * 64 + c] = __float2bfloat16(src[c] * scale);
}

// ---------------------------------------------------------------------------
// K0b: xT[b*4+f][n][64] = bf16( x[c][n] * gamma[c]/sqrt(1+eps) + beta[c] )
// transposed through LDS; coalesced f32 reads, contiguous bf16 row writes.
// ---------------------------------------------------------------------------
__global__ __launch_bounds__(256) void xt_kernel(const float* __restrict__ xs,
                                                 const float* __restrict__ gamma,
                                                 const float* __restrict__ beta,
                                                 __hip_bfloat16* __restrict__ xT) {
    const int fr = blockIdx.y;             // b*4 + f
    const int n0 = blockIdx.x * 64;
    const float* __restrict__ A = xs + (size_t)fr * 64 * NPTS;   // [c][n]

    __shared__ float As[64][68];
    __shared__ float sg[64], sb[64];

    const int t = threadIdx.x;
    if (t < 64) {
        const float inv = 1.0f / sqrtf(1.0f + 1e-5f);
        sg[t] = gamma[t] * inv;
        sb[t] = beta[t];
    }
    const int tx = t & 15, ty = t >> 4;
    for (int r = 0; r < 4; ++r) {
        int row = ty + 16 * r, col = tx * 4;
        *(float4*)&As[row][col] = *(const float4*)&A[(size_t)row * NPTS + n0 + col];
    }
    __syncthreads();

    const int nl = t >> 2, c0 = (t & 3) * 16;
    bf16x8 v0, v1;
#pragma unroll
    for (int j = 0; j < 8; ++j) {
        float a = As[c0 + j][nl] * sg[c0 + j] + sb[c0 + j];
        v0[j] = (short)__bfloat16_as_ushort(__float2bfloat16(a));
    }
#pragma unroll
    for (int j = 0; j < 8; ++j) {
        float a = As[c0 + 8 + j][nl] * sg[c0 + 8 + j] + sb[c0 + 8 + j];
        v1[j] = (short)__bfloat16_as_ushort(__float2bfloat16(a));
    }
    __hip_bfloat16* dst = xT + ((size_t)fr * NPTS + n0 + nl) * 64 + c0;
    *(bf16x8*)(dst) = v0;
    *(bf16x8*)(dst + 8) = v1;
}

// ---------------------------------------------------------------------------
// K1: QKV via MFMA, zero LDS.  A/B fragments are contiguous bf16x8 global
// loads (xT rows, Wpb rows — both L2-resident).
//   jt<8 (Q/K):  D[j][n] = mfma(wf, xf)  -> store 4 consecutive j at Qg[n][.]
//   jt>=8 (V):   D[n][j] = mfma(xf, wf)  -> store 4 consecutive n at Vt[c][.]
// ---------------------------------------------------------------------------
__global__ __launch_bounds__(256) void qkv_mfma(const __hip_bfloat16* __restrict__ xT,
                                                const __hip_bfloat16* __restrict__ Wpb,
                                                __hip_bfloat16* __restrict__ Qg,
                                                __hip_bfloat16* __restrict__ Kg,
                                                __hip_bfloat16* __restrict__ Vtg) {
    const int bf = blockIdx.z;            // b*2 + f01
    const int b = bf >> 1, f01 = bf & 1;
    const int jt = blockIdx.y;            // 0..11
    const int f_src = (jt < 4) ? f01 : (3 - f01);
    const int n0 = blockIdx.x * 64;

    const int t = threadIdx.x, lane = t & 63, w = t >> 6;
    const int l15 = lane & 15, g = (lane >> 4) & 3;

    const __hip_bfloat16* __restrict__ xfb = xT + (size_t)(b * 4 + f_src) * NPTS * 64;

    if (jt < 8) {
        // wave w owns j-sub w: rows j = (jt&3)*64 + w*16 + 0..15
        const __hip_bfloat16* wp = Wpb + (size_t)(jt * 64 + w * 16 + l15) * 64 + g * 8;
        bf16x8 wf0 = *(const bf16x8*)(wp);
        bf16x8 wf1 = *(const bf16x8*)(wp + 32);
        __hip_bfloat16* __restrict__ dst = (jt < 4 ? Qg : Kg) + (size_t)bf * NPTS * 256;
        const int jb = (jt & 3) * 64 + w * 16 + g * 4;
#pragma unroll
        for (int nt = 0; nt < 4; ++nt) {
            const __hip_bfloat16* xp = xfb + (size_t)(n0 + nt * 16 + l15) * 64 + g * 8;
            bf16x8 xf0 = *(const bf16x8*)(xp);
            bf16x8 xf1 = *(const bf16x8*)(xp + 32);
            f32x4 d = (f32x4){0.f, 0.f, 0.f, 0.f};
            d = __builtin_amdgcn_mfma_f32_16x16x32_bf16(wf0, xf0, d, 0, 0, 0);
            d = __builtin_amdgcn_mfma_f32_16x16x32_bf16(wf1, xf1, d, 0, 0, 0);
            uint2 pv;
            pv.x = cvt_pk_bf16(d[0], d[1]);
            pv.y = cvt_pk_bf16(d[2], d[3]);
            *(uint2*)&dst[(size_t)(n0 + nt * 16 + l15) * 256 + jb] = pv;
        }
    } else {
        // V: wave w owns n-sub w: rows n = n0 + w*16 + 0..15
        const __hip_bfloat16* xp = xfb + (size_t)(n0 + w * 16 + l15) * 64 + g * 8;
        bf16x8 xf0 = *(const bf16x8*)(xp);
        bf16x8 xf1 = *(const bf16x8*)(xp + 32);
        __hip_bfloat16* __restrict__ dst = Vtg + (size_t)bf * 256 * NPTS;
#pragma unroll
        for (int tj = 0; tj < 4; ++tj) {
            const int ch = (jt - 8) * 64 + tj * 16 + l15;
            const __hip_bfloat16* wp = Wpb + (size_t)(512 + ch) * 64 + g * 8;
            bf16x8 wf0 = *(const bf16x8*)(wp);
            bf16x8 wf1 = *(const bf16x8*)(wp + 32);
            f32x4 d = (f32x4){0.f, 0.f, 0.f, 0.f};
            d = __builtin_amdgcn_mfma_f32_16x16x32_bf16(xf0, wf0, d, 0, 0, 0);
            d = __builtin_amdgcn_mfma_f32_16x16x32_bf16(xf1, wf1, d, 0, 0, 0);
            uint2 pv;
            pv.x = cvt_pk_bf16(d[0], d[1]);
            pv.y = cvt_pk_bf16(d[2], d[3]);
            *(uint2*)&dst[(size_t)ch * NPTS + n0 + w * 16 + g * 4] = pv;
        }
    }
}

// ---------------------------------------------------------------------------
// K2: MFMA flash attention (unchanged from round-8 verified version).
// ---------------------------------------------------------------------------
__global__ __launch_bounds__(256, 4) void attn_mfma(const __hip_bfloat16* __restrict__ Qg,
                                                    const __hip_bfloat16* __restrict__ Kg,
                                                    const __hip_bfloat16* __restrict__ Vtg,
                                                    __hip_bfloat16* __restrict__ OTb,
                                                    float* __restrict__ Lp) {
    const int combo = blockIdx.x;          // bf*4 + h
    const int bf = combo >> 2, h = combo & 3;
    const int n0 = blockIdx.y * 128;
    const int split = blockIdx.z;
    const int kbase = split * (NPTS / KSPLIT);
    const int NT = NPTS / KSPLIT / 32;     // 8 k-tiles of 32 per split

    __shared__ __align__(16) char smem[32768];   // 4 bufs x (K 4KB | V 4KB)

    const int t = threadIdx.x;
    const int lane = t & 63, w = t >> 6;
    const int l15 = lane & 15, g = (lane >> 4) & 3;

    const int krow = w * 8 + (lane >> 3), kslot = lane & 7;
    const int vrow = w * 16 + (lane >> 2), vslot = lane & 3;
    const int kcs = (kslot ^ (krow & 7)) * 8;
    const int vcs = (vslot ^ ((vrow >> 1) & 3)) * 8;

    const __hip_bfloat16* qbase =
        Qg + ((size_t)bf * NPTS + n0 + w * 32 + l15) * 256 + h * 64 + g * 8;
    bf16x8 qf[2][2];
    qf[0][0] = *(const bf16x8*)(qbase);
    qf[0][1] = *(const bf16x8*)(qbase + 32);
    qf[1][0] = *(const bf16x8*)(qbase + 16 * 256);
    qf[1][1] = *(const bf16x8*)(qbase + 16 * 256 + 32);

    const __hip_bfloat16* kgb = Kg + (size_t)bf * NPTS * 256 + h * 64;
    const __hip_bfloat16* vgb = Vtg + ((size_t)bf * 256 + h * 64) * NPTS;

    int koff[2][2], voff[4];
#pragma unroll
    for (int tt = 0; tt < 2; ++tt) {
        const int row = tt * 16 + l15;
#pragma unroll
        for (int s = 0; s < 2; ++s)
            koff[tt][s] = row * 128 + (((s * 4 + g) ^ (row & 7)) << 4);
    }
#pragma unroll
    for (int ct = 0; ct < 4; ++ct) {
        const int row = ct * 16 + l15;
        voff[ct] = 4096 + row * 64 + ((g ^ ((row >> 1) & 3)) << 4);
    }

    f32x4 oacc[2][4];
    float lsum[2] = {0.f, 0.f};
#pragma unroll
    for (int f = 0; f < 2; ++f)
#pragma unroll
        for (int r = 0; r < 4; ++r) oacc[f][r] = (f32x4){0.f, 0.f, 0.f, 0.f};

    auto stage = [&](int kt) {
        const int bsel = kt & 3;
        const __hip_bfloat16* ksrc = kgb + (size_t)(kbase + kt * 32 + krow) * 256 + kcs;
        __builtin_amdgcn_global_load_lds((const glob_char*)ksrc,
            (lds_char*)(smem + bsel * 8192 + w * 1024), 16, 0, 0);
        const __hip_bfloat16* vsrc = vgb + (size_t)vrow * NPTS + kbase + kt * 32 + vcs;
        __builtin_amdgcn_global_load_lds((const glob_char*)vsrc,
            (lds_char*)(smem + bsel * 8192 + 4096 + w * 1024), 16, 0, 0);
    };

    auto tile = [&](int kt) {
        const char* B = smem + (kt & 3) * 8192;
        bf16x8 kf[2][2];
#pragma unroll
        for (int tt = 0; tt < 2; ++tt)
#pragma unroll
            for (int s = 0; s < 2; ++s)
                kf[tt][s] = *(const bf16x8*)(B + koff[tt][s]);

        bf16x8 pb[2];
#pragma unroll
        for (int f = 0; f < 2; ++f) {
            f32x4 st0 = (f32x4){0.f, 0.f, 0.f, 0.f}, st1 = st0;
            st0 = __builtin_amdgcn_mfma_f32_16x16x32_bf16(kf[0][0], qf[f][0], st0, 0, 0, 0);
            st0 = __builtin_amdgcn_mfma_f32_16x16x32_bf16(kf[0][1], qf[f][1], st0, 0, 0, 0);
            st1 = __builtin_amdgcn_mfma_f32_16x16x32_bf16(kf[1][0], qf[f][0], st1, 0, 0, 0);
            st1 = __builtin_amdgcn_mfma_f32_16x16x32_bf16(kf[1][1], qf[f][1], st1, 0, 0, 0);
            float p00 = exp2f(st0[0]);
            float p01 = exp2f(st0[1]);
            float p02 = exp2f(st0[2]);
            float p03 = exp2f(st0[3]);
            float p10 = exp2f(st1[0]);
            float p11 = exp2f(st1[1]);
            float p12 = exp2f(st1[2]);
            float p13 = exp2f(st1[3]);
            lsum[f] += ((p00 + p01) + (p02 + p03)) + ((p10 + p11) + (p12 + p13));
            unsigned x0 = cvt_pk_bf16(p00, p01);
            unsigned x1 = cvt_pk_bf16(p02, p03);
            unsigned y0 = cvt_pk_bf16(p10, p11);
            unsigned y1 = cvt_pk_bf16(p12, p13);
            asm("v_permlane32_swap_b32 %0, %1" : "+v"(x0), "+v"(y0));
            asm("v_permlane16_swap_b32 %0, %1" : "+v"(x0), "+v"(y0));
            asm("v_permlane32_swap_b32 %0, %1" : "+v"(x1), "+v"(y1));
            asm("v_permlane16_swap_b32 %0, %1" : "+v"(x1), "+v"(y1));
            PBU pu;
            pu.u = (uint32x4){x0, x1, y0, y1};
            pb[f] = pu.v;
        }

#pragma unroll
        for (int ct = 0; ct < 4; ++ct) {
            bf16x8 vf = *(const bf16x8*)(B + voff[ct]);
            oacc[0][ct] = __builtin_amdgcn_mfma_f32_16x16x32_bf16(vf, pb[0], oacc[0][ct], 0, 0, 0);
            oacc[1][ct] = __builtin_amdgcn_mfma_f32_16x16x32_bf16(vf, pb[1], oacc[1][ct], 0, 0, 0);
        }
    };

    stage(0);
    stage(1);
    for (int kt = 0; kt < NT - 2; ++kt) {
        stage(kt + 2);
        asm volatile("s_waitcnt vmcnt(4)" ::: "memory");
        asm volatile("s_waitcnt lgkmcnt(0)" ::: "memory");
        __builtin_amdgcn_s_barrier();
        asm volatile("" ::: "memory");
        tile(kt);
    }
    asm volatile("s_waitcnt vmcnt(2)" ::: "memory");
    asm volatile("s_waitcnt lgkmcnt(0)" ::: "memory");
    __builtin_amdgcn_s_barrier();
    asm volatile("" ::: "memory");
    tile(NT - 2);
    asm volatile("s_waitcnt vmcnt(0)" ::: "memory");
    asm volatile("s_waitcnt lgkmcnt(0)" ::: "memory");
    __builtin_amdgcn_s_barrier();
    asm volatile("" ::: "memory");
    tile(NT - 1);

    float l0 = lsum[0], l1 = lsum[1];
    l0 += __shfl_xor(l0, 16);
    l0 += __shfl_xor(l0, 32);
    l1 += __shfl_xor(l1, 16);
    l1 += __shfl_xor(l1, 32);
    const int qq = n0 + w * 32 + l15;
    if (lane < 16) {
        Lp[(size_t)(split * 16 + combo) * NPTS + qq] = l0;
        Lp[(size_t)(split * 16 + combo) * NPTS + qq + 16] = l1;
    }

    __hip_bfloat16* __restrict__ Op = OTb + (size_t)(split * 16 + combo) * 64 * NPTS;
#pragma unroll
    for (int ct = 0; ct < 4; ++ct)
#pragma unroll
        for (int r = 0; r < 4; ++r) {
            Op[(size_t)(ct * 16 + g * 4 + r) * NPTS + qq] = __float2bfloat16(oacc[0][ct][r]);
            Op[(size_t)(ct * 16 + g * 4 + r) * NPTS + qq + 16] = __float2bfloat16(oacc[1][ct][r]);
        }
}

// ---------------------------------------------------------------------------
// K3: combine KSPLIT attention partials + normalize, then
//     xa = (O_f0 + O_f1) @ proj_w.T + proj_b ; frames = xa @ map_w.T + map_b
// ---------------------------------------------------------------------------
__global__ __launch_bounds__(256) void proj_frames(const __hip_bfloat16* __restrict__ OTb,
                                                   const float* __restrict__ Lp,
                                                   const float* __restrict__ proj_w,
                                                   const float* __restrict__ proj_b,
                                                   const float* __restrict__ map_w,
                                                   const float* __restrict__ map_b,
                                                   float* __restrict__ out,
                                                   float* __restrict__ frames0) {
    const int bh = blockIdx.y, b = bh >> 2, h = bh & 3;
    const int n0 = blockIdx.x * 64;
    const int cf0 = (b * 2 + 0) * 4 + h;
    const int cf1 = (b * 2 + 1) * 4 + h;

    __shared__ float Xs[64][68];   // [c][n]
    __shared__ float Ws[64][68];   // [j][c]
    __shared__ float xaS[64][68];  // [n][j]

    const int t = threadIdx.x;
    const int tx = t & 15, ty = t >> 4;
    const int nc = n0 + tx * 4;

    float4 L0 = make_float4(0.f, 0.f, 0.f, 0.f), L1 = L0;
#pragma unroll
    for (int s = 0; s < KSPLIT; ++s) {
        float4 a = *(const float4*)&Lp[(size_t)(s * 16 + cf0) * NPTS + nc];
        L0.x += a.x; L0.y += a.y; L0.z += a.z; L0.w += a.w;
        float4 c = *(const float4*)&Lp[(size_t)(s * 16 + cf1) * NPTS + nc];
        L1.x += c.x; L1.y += c.y; L1.z += c.z; L1.w += c.w;
    }
    float4 inv0 = make_float4(1.f / L0.x, 1.f / L0.y, 1.f / L0.z, 1.f / L0.w);
    float4 inv1 = make_float4(1.f / L1.x, 1.f / L1.y, 1.f / L1.z, 1.f / L1.w);

    for (int r = 0; r < 4; ++r) {
        int row = ty + 16 * r, col = tx * 4;   // row = c, col = n_local
        float x0 = 0.f, x1 = 0.f, x2 = 0.f, x3 = 0.f;
        float y0 = 0.f, y1 = 0.f, y2 = 0.f, y3 = 0.f;
#pragma unroll
        for (int s = 0; s < KSPLIT; ++s) {
            ushort4 u0 = *(const ushort4*)&OTb[((size_t)(s * 16 + cf0) * 64 + row) * NPTS + n0 + col];
            ushort4 u1 = *(const ushort4*)&OTb[((size_t)(s * 16 + cf1) * 64 + row) * NPTS + n0 + col];
            x0 += b2f(u0.x); x1 += b2f(u0.y); x2 += b2f(u0.z); x3 += b2f(u0.w);
            y0 += b2f(u1.x); y1 += b2f(u1.y); y2 += b2f(u1.z); y3 += b2f(u1.w);
        }
        Xs[row][col + 0] = x0 * inv0.x + y0 * inv1.x;
        Xs[row][col + 1] = x1 * inv0.y + y1 * inv1.y;
        Xs[row][col + 2] = x2 * inv0.z + y2 * inv1.z;
        Xs[row][col + 3] = x3 * inv0.w + y3 * inv1.w;
        *(float4*)&Ws[row][col] = *(const float4*)&proj_w[(size_t)row * 64 + col];
    }
    __syncthreads();

    float acc[4][4];
#pragma unroll
    for (int jj = 0; jj < 4; ++jj) {
        float bv = proj_b[tx + 16 * jj];
#pragma unroll
        for (int i = 0; i < 4; ++i) acc[i][jj] = bv;
    }
    for (int c = 0; c < 64; ++c) {
        float a[4], w[4];
#pragma unroll
        for (int i = 0; i < 4; ++i) a[i] = Xs[c][ty + 16 * i];
#pragma unroll
        for (int jj = 0; jj < 4; ++jj) w[jj] = Ws[tx + 16 * jj][c];
#pragma unroll
        for (int i = 0; i < 4; ++i)
#pragma unroll
            for (int jj = 0; jj < 4; ++jj) acc[i][jj] += a[i] * w[jj];
    }

#pragma unroll
    for (int i = 0; i < 4; ++i)
#pragma unroll
        for (int jj = 0; jj < 4; ++jj)
            xaS[ty + 16 * i][tx + 16 * jj] = acc[i][jj];

    if (h >= 1) {
        float* __restrict__ xa_out = out + (size_t)(b * 3 + h - 1) * NPTS * 64;
#pragma unroll
        for (int i = 0; i < 4; ++i)
#pragma unroll
            for (int jj = 0; jj < 4; ++jj)
                xa_out[(size_t)(n0 + ty + 16 * i) * 64 + tx + 16 * jj] = acc[i][jj];
    }
    __syncthreads();

    if (t < 192) {
        int r = t / 3, j = t % 3;
        float s = map_b[j];
        for (int c = 0; c < 64; ++c) s += xaS[r][c] * map_w[j * 64 + c];
        int n = n0 + r;
        if (h == 0) frames0[((size_t)b * NPTS + n) * 3 + j] = s;
        else        out[786432 + ((size_t)(b * 3 + h - 1) * NPTS + n) * 3 + j] = s;
    }
}

// ---------------------------------------------------------------------------
// K4a: chamfer partial mins.  grid (NPTS/256, NJC, 4); z = dir*2 + b.
// ---------------------------------------------------------------------------
__global__ __launch_bounds__(256) void chamfer_partial(const float* __restrict__ pc1,
                                                       const float* __restrict__ frames0,
                                                       float* __restrict__ partial) {
    const int z = blockIdx.z;          // dir*2 + b
    const int dir = z >> 1, b = z & 1;
    const int i = blockIdx.x * 256 + threadIdx.x;
    const int j0 = blockIdx.y * JCH;
    const float* __restrict__ px = pc1 + (size_t)b * 3 * NPTS;
    const float* __restrict__ fr = frames0 + (size_t)b * NPTS * 3;

    __shared__ float4 sj[JCH];
    if (threadIdx.x < JCH) {
        int jj = j0 + threadIdx.x;
        float bx = px[jj], by = px[NPTS + jj], bz = px[2 * NPTS + jj];
        if (dir == 1) { bx += fr[jj * 3]; by += fr[jj * 3 + 1]; bz += fr[jj * 3 + 2]; }
        sj[threadIdx.x] = make_float4(bx, by, bz, bx * bx + by * by + bz * bz);
    }
    float ax = px[i], ay = px[NPTS + i], az = px[2 * NPTS + i];
    if (dir == 0) { ax += fr[i * 3]; ay += fr[i * 3 + 1]; az += fr[i * 3 + 2]; }
    const float a2 = ax * ax + ay * ay + az * az;
    __syncthreads();

    float best = 1e30f;
#pragma unroll 4
    for (int k = 0; k < JCH; ++k) {
        float4 p = sj[k];
        float d = a2 + p.w - 2.0f * (ax * p.x + ay * p.y + az * p.z);
        best = fminf(best, d);
    }
    partial[((size_t)z * NJC + blockIdx.y) * NPTS + i] = best;
}

// ---------------------------------------------------------------------------
// K4b: min over chunks + per-block sum. 32 blocks x 256 thr.
// ---------------------------------------------------------------------------
__global__ __launch_bounds__(256) void chamfer_minsum(const float* __restrict__ partial,
                                                      double* __restrict__ sums) {
    const int gid = blockIdx.x * 256 + threadIdx.x;
    const int z = gid >> 11, i = gid & 2047;
    float best = 1e30f;
#pragma unroll
    for (int c = 0; c < NJC; ++c)
        best = fminf(best, partial[((size_t)z * NJC + c) * NPTS + i]);
    __shared__ double sm[256];
    sm[threadIdx.x] = (double)best;
    __syncthreads();
    for (int off = 128; off > 0; off >>= 1) {
        if (threadIdx.x < off) sm[threadIdx.x] += sm[threadIdx.x + off];
        __syncthreads();
    }
    if (threadIdx.x == 0) sums[blockIdx.x] = sm[0];
}

__global__ void chamfer_final(const double* __restrict__ sums, float* __restrict__ loss_out) {
    if (threadIdx.x == 0) {
        double s = 0.0;
        for (int k = 0; k < 32; ++k) s += sums[k];
        loss_out[0] = (float)(s / 4096.0);
    }
}

// ---------------------------------------------------------------------------
extern "C" void kernel_launch(void* const* d_in, const int* in_sizes, int n_in,
                              void* d_out, int out_size, void* d_ws, size_t ws_size,
                              hipStream_t stream) {
    const float* xs     = (const float*)d_in[0];
    const float* pc1    = (const float*)d_in[1];
    // d_in[2] = pc2 (unused by reference)
    const float* gamma  = (const float*)d_in[3];
    const float* beta   = (const float*)d_in[4];
    const float* q_w    = (const float*)d_in[5];
    const float* kv_w   = (const float*)d_in[6];
    const float* proj_w = (const float*)d_in[7];
    const float* proj_b = (const float*)d_in[8];
    const float* map_w  = (const float*)d_in[9];
    const float* map_b  = (const float*)d_in[10];
    float* out = (float*)d_out;

    char* ws = (char*)d_ws;
    __hip_bfloat16* Qg  = (__hip_bfloat16*)(ws);              // 4 MiB
    __hip_bfloat16* Kg  = (__hip_bfloat16*)(ws + 4194304);    // 4 MiB
    __hip_bfloat16* Vtg = (__hip_bfloat16*)(ws + 8388608);    // 4 MiB
    __hip_bfloat16* OTb = (__hip_bfloat16*)(ws + 12582912);   // 32 MiB
    __hip_bfloat16* Wpb = (__hip_bfloat16*)(ws + 46137344);   // 96 KiB
    __hip_bfloat16* xT  = (__hip_bfloat16*)(ws + 46235648);   // 2 MiB
    float* frames0 = (float*)(ws + 48332800);                 // 48 KiB
    float* partial = (float*)(ws + 48381952);                 // 512 KiB
    double* sums   = (double*)(ws + 48906240);                // 256 B
    float* Lp      = (float*)(ws + 48906496);                 // 1 MiB

    hipLaunchKernelGGL(prep_weights, dim3(3), dim3(256), 0, stream,
                       q_w, kv_w, Wpb);
    hipLaunchKernelGGL(xt_kernel, dim3(32, 8), dim3(256), 0, stream,
                       xs, gamma, beta, xT);
    hipLaunchKernelGGL(qkv_mfma, dim3(32, 12, 4), dim3(256), 0, stream,
                       xT, Wpb, Qg, Kg, Vtg);
    hipLaunchKernelGGL(attn_mfma, dim3(16, 16, KSPLIT), dim3(256), 0, stream,
                       Qg, Kg, Vtg, OTb, Lp);
    hipLaunchKernelGGL(proj_frames, dim3(32, 8), dim3(256), 0, stream,
                       OTb, Lp, proj_w, proj_b, map_w, map_b, out, frames0);
    hipLaunchKernelGGL(chamfer_partial, dim3(NPTS / 256, NJC, 4), dim3(256), 0, stream,
                       pc1, frames0, partial);
    hipLaunchKernelGGL(chamfer_minsum, dim3(32), dim3(256), 0, stream,
                       partial, sums);
    hipLaunchKernelGGL(chamfer_final, dim3(1), dim3(64), 0, stream,
                       sums, out + 823296);
}